// Round 9
// baseline (546.041 us; speedup 1.0000x reference)
//
#include <hip/hip_runtime.h>
#include <hip/hip_fp16.h>

#define NEG_SLOPE 0.2f

typedef __attribute__((ext_vector_type(8))) short bf16x8;
typedef __attribute__((ext_vector_type(4))) float f32x4;

__device__ __forceinline__ unsigned short f2bf_rne(float x) {
    unsigned int u = __float_as_uint(x);
    unsigned int r = (u + 0x7FFFu + ((u >> 16) & 1u)) >> 16;
    return (unsigned short)r;
}

__device__ __forceinline__ void gload_lds16(const unsigned short* g, unsigned short* lds) {
    __builtin_amdgcn_global_load_lds(
        (const __attribute__((address_space(1))) void*)g,
        (__attribute__((address_space(3))) void*)lds, 16, 0, 0);
}

__device__ __forceinline__ void h8_to_f(const uint4 v, float* f) {
    const __half2* hp = reinterpret_cast<const __half2*>(&v);
    float2 t0 = __half22float2(hp[0]);
    float2 t1 = __half22float2(hp[1]);
    float2 t2 = __half22float2(hp[2]);
    float2 t3 = __half22float2(hp[3]);
    f[0] = t0.x; f[1] = t0.y; f[2] = t1.x; f[3] = t1.y;
    f[4] = t2.x; f[5] = t2.y; f[6] = t3.x; f[7] = t3.y;
}

// ---------------------------------------------------------------------------
// CSR build
// ---------------------------------------------------------------------------

__global__ void detect_i64_kernel(const unsigned int* __restrict__ w, int E, int* __restrict__ flag) {
    __shared__ unsigned int ssum[256];
    int n = E < 4096 ? E : 4096;
    unsigned int local = 0;
    for (int k = threadIdx.x; k < n; k += 256) local |= w[2 * k + 1];
    ssum[threadIdx.x] = local;
    __syncthreads();
    for (int off = 128; off > 0; off >>= 1) {
        if (threadIdx.x < off) ssum[threadIdx.x] |= ssum[threadIdx.x + off];
        __syncthreads();
    }
    if (threadIdx.x == 0) flag[0] = (ssum[0] == 0) ? 1 : 0;
}

__global__ void count_deg_kernel(const void* __restrict__ eiv, int E,
                                 const int* __restrict__ flag, int* __restrict__ deg) {
    int e = blockIdx.x * blockDim.x + threadIdx.x;
    if (e >= E) return;
    int d;
    if (*flag) d = (int)((const long long*)eiv)[(size_t)E + e];
    else       d = ((const int*)eiv)[(size_t)E + e];
    atomicAdd(&deg[d], 1);
}

__global__ void scan_block_kernel(const int* __restrict__ deg, int* __restrict__ row_ptr,
                                  int* __restrict__ partial, int N) {
    __shared__ int sd[1024];
    int t = threadIdx.x;
    int g = blockIdx.x * 1024 + t;
    int v = (g < N) ? deg[g] : 0;
    sd[t] = v;
    __syncthreads();
    for (int off = 1; off < 1024; off <<= 1) {
        int add = (t >= off) ? sd[t - off] : 0;
        __syncthreads();
        sd[t] += add;
        __syncthreads();
    }
    if (g < N) row_ptr[g + 1] = sd[t];
    if (t == 1023) partial[blockIdx.x] = sd[1023];
    if (g == 0) row_ptr[0] = 0;
}

__global__ void scan_top_kernel(int* __restrict__ partial, int nb) {
    if (threadIdx.x == 0 && blockIdx.x == 0) {
        int run = 0;
        for (int j = 0; j < nb; ++j) { run += partial[j]; partial[j] = run; }
    }
}

__global__ void scan_addoff_kernel(int* __restrict__ row_ptr, const int* __restrict__ partial, int N) {
    int g = blockIdx.x * 256 + threadIdx.x;
    if (g >= N) return;
    int b = g >> 10;
    if (b > 0) row_ptr[g + 1] += partial[b - 1];
}

__global__ void scatter_kernel(const void* __restrict__ eiv, int E,
                               const int* __restrict__ flag,
                               const int* __restrict__ row_ptr,
                               int* __restrict__ cursor, int* __restrict__ csr) {
    int e = blockIdx.x * blockDim.x + threadIdx.x;
    if (e >= E) return;
    int s, d;
    if (*flag) {
        s = (int)((const long long*)eiv)[e];
        d = (int)((const long long*)eiv)[(size_t)E + e];
    } else {
        s = ((const int*)eiv)[e];
        d = ((const int*)eiv)[(size_t)E + e];
    }
    int pos = atomicAdd(&cursor[d], 1);
    csr[row_ptr[d] + pos] = s;
}

// ---------------------------------------------------------------------------
// fp32 -> bf16 hi/lo split
// ---------------------------------------------------------------------------

__global__ void split_kernel(const float* __restrict__ src, int n4,
                             unsigned short* __restrict__ hi, unsigned short* __restrict__ lo) {
    int i = blockIdx.x * blockDim.x + threadIdx.x;
    if (i >= n4) return;
    float4 v = *reinterpret_cast<const float4*>(&src[(size_t)i * 4]);
    ushort4 h, l;
    float f;
    h.x = f2bf_rne(v.x); f = v.x - __uint_as_float((unsigned int)h.x << 16); l.x = f2bf_rne(f);
    h.y = f2bf_rne(v.y); f = v.y - __uint_as_float((unsigned int)h.y << 16); l.y = f2bf_rne(f);
    h.z = f2bf_rne(v.z); f = v.z - __uint_as_float((unsigned int)h.z << 16); l.z = f2bf_rne(f);
    h.w = f2bf_rne(v.w); f = v.w - __uint_as_float((unsigned int)h.w << 16); l.w = f2bf_rne(f);
    *reinterpret_cast<ushort4*>(&hi[(size_t)i * 4]) = h;
    *reinterpret_cast<ushort4*>(&lo[(size_t)i * 4]) = l;
}

__global__ void splitT_w_kernel(const float* __restrict__ Wl, const float* __restrict__ Wr, int M,
                                unsigned short* __restrict__ WThi, unsigned short* __restrict__ WTlo) {
    int k = blockIdx.x;
    int m2 = blockIdx.y * 256 + threadIdx.x;
    if (m2 >= 2 * M) return;
    float v = (m2 < M) ? Wl[(size_t)k * M + m2] : Wr[(size_t)k * M + (m2 - M)];
    unsigned short h = f2bf_rne(v);
    float fl = v - __uint_as_float((unsigned int)h << 16);
    WThi[(size_t)m2 * 256 + k] = h;
    WTlo[(size_t)m2 * 256 + k] = f2bf_rne(fl);
}

// ---------------------------------------------------------------------------
// MFMA GEMM (split-bf16, 3 passes), tile 128x128, BK=64, single-buffered A in
// LDS (32 KB -> 4 blocks/CU with __launch_bounds__(256,4)). B (weights,
// L2-resident) read directly global->register per ksub — no B staging.
// A staged via global_load_lds with pre-swizzled global source (R7-proven).
// Epilogue: cols [0,M) -> fp16 xl buffer; cols [M,2M) -> fp32 xr buffer.
// ---------------------------------------------------------------------------

__global__ __launch_bounds__(256, 4) void gemm_mfma_kernel(
    const unsigned short* __restrict__ Ahi, const unsigned short* __restrict__ Alo,
    const unsigned short* __restrict__ Bhi, const unsigned short* __restrict__ Blo,
    __half* __restrict__ xl16, float* __restrict__ xr32, int N, int M) {
    __shared__ unsigned short sA[2][128 * 64];

    int t = threadIdx.x;
    int lane = t & 63;
    int w = t >> 6;
    int wr = (w >> 1) * 64;
    int wc = (w & 1) * 64;
    int row0 = blockIdx.x * 128;
    int n0 = blockIdx.y * 128;

    int l15 = lane & 15;
    int l4 = lane >> 4;

    int lr8 = lane >> 3;
    int lc8 = lane & 7;
    int ksw = (lc8 ^ lr8) * 8;

    f32x4 acc[4][4] = {};

    for (int k0 = 0; k0 < 256; k0 += 64) {
        __syncthreads();
        #pragma unroll
        for (int i = 0; i < 4; ++i) {
            int brow = i * 32 + w * 8;
            int row = brow + lr8;
            int ar = row0 + row; if (ar >= N) ar = N - 1;
            gload_lds16(&Ahi[(size_t)ar * 256 + k0 + ksw], &sA[0][brow * 64]);
            gload_lds16(&Alo[(size_t)ar * 256 + k0 + ksw], &sA[1][brow * 64]);
        }
        __syncthreads();

        #pragma unroll
        for (int ksub = 0; ksub < 2; ++ksub) {
            int kb = ksub * 32 + l4 * 8;
            // A fragments from LDS (reused across fc)
            bf16x8 ah[4], al[4];
            #pragma unroll
            for (int fr = 0; fr < 4; ++fr) {
                int r = wr + fr * 16 + l15;
                int idx = r * 64 + (kb ^ ((r & 7) << 3));
                ah[fr] = *reinterpret_cast<const bf16x8*>(&sA[0][idx]);
                al[fr] = *reinterpret_cast<const bf16x8*>(&sA[1][idx]);
            }
            #pragma unroll
            for (int fc = 0; fc < 4; ++fc) {
                int col = n0 + wc + fc * 16 + l15;
                bf16x8 bh = *reinterpret_cast<const bf16x8*>(&Bhi[(size_t)col * 256 + k0 + kb]);
                bf16x8 bl = *reinterpret_cast<const bf16x8*>(&Blo[(size_t)col * 256 + k0 + kb]);
                #pragma unroll
                for (int fr = 0; fr < 4; ++fr) {
                    acc[fr][fc] = __builtin_amdgcn_mfma_f32_16x16x32_bf16(ah[fr], bh, acc[fr][fc], 0, 0, 0);
                    acc[fr][fc] = __builtin_amdgcn_mfma_f32_16x16x32_bf16(ah[fr], bl, acc[fr][fc], 0, 0, 0);
                    acc[fr][fc] = __builtin_amdgcn_mfma_f32_16x16x32_bf16(al[fr], bh, acc[fr][fc], 0, 0, 0);
                }
            }
        }
    }

    #pragma unroll
    for (int fr = 0; fr < 4; ++fr) {
        #pragma unroll
        for (int j = 0; j < 4; ++j) {
            int row = row0 + wr + fr * 16 + l4 * 4 + j;
            if (row < N) {
                #pragma unroll
                for (int fc = 0; fc < 4; ++fc) {
                    int col = n0 + wc + fc * 16 + l15;
                    float v = acc[fr][fc][j];
                    if (col < M) xl16[(size_t)row * M + col] = __float2half(v);
                    else         xr32[(size_t)row * M + (col - M)] = v;
                }
            }
        }
    }
}

// ---------------------------------------------------------------------------
// agg_h8: one wave per node; half = lane>>5 picks edge slot, lane&31 owns
// 8 channels. xl gathered as fp16 (one 16B load/lane/edge); xr read fp32 once.
// Fixed-m softmax (m = self logit), 1-deep pipeline.
// ---------------------------------------------------------------------------

__global__ __launch_bounds__(256) void agg_h8_kernel(
    const __half* __restrict__ xl16, const float* __restrict__ xr32,
    const float* __restrict__ att, const float* __restrict__ bias,
    const int* __restrict__ row_ptr, const int* __restrict__ csr,
    unsigned short* __restrict__ ohi, unsigned short* __restrict__ olo, int N) {
    int wv = threadIdx.x >> 6;
    int i = blockIdx.x * 4 + wv;
    if (i >= N) return;
    int lane = threadIdx.x & 63;
    int half = lane >> 5;
    int cb = (lane & 31) * 8;

    float rxr[8], a6[8], a4[8];
    {
        float4 r0 = *reinterpret_cast<const float4*>(&xr32[(size_t)i * 256 + cb]);
        float4 r1 = *reinterpret_cast<const float4*>(&xr32[(size_t)i * 256 + cb + 4]);
        rxr[0] = r0.x; rxr[1] = r0.y; rxr[2] = r0.z; rxr[3] = r0.w;
        rxr[4] = r1.x; rxr[5] = r1.y; rxr[6] = r1.z; rxr[7] = r1.w;
        float4 w0 = *reinterpret_cast<const float4*>(&att[cb]);
        float4 w1 = *reinterpret_cast<const float4*>(&att[cb + 4]);
        float aa[8] = {w0.x, w0.y, w0.z, w0.w, w1.x, w1.y, w1.z, w1.w};
        #pragma unroll
        for (int c = 0; c < 8; ++c) { a6[c] = 0.6f * aa[c]; a4[c] = 0.4f * aa[c]; }
    }

    float acc[8], l, m;
    {
        uint4 sv = *reinterpret_cast<const uint4*>(&xl16[(size_t)i * 256 + cb]);
        float u[8];
        h8_to_f(sv, u);
        float p = 0.f;
        #pragma unroll
        for (int c = 0; c < 8; ++c) {
            float v = u[c] + rxr[c];
            p = fmaf(a6[c], v, p);
            p = fmaf(a4[c], fabsf(v), p);
        }
        p += __shfl_xor(p, 1, 4);
        p += __shfl_xor(p, 2, 4);
        m = p;
        l = half ? 0.f : 1.f;
        #pragma unroll
        for (int c = 0; c < 8; ++c) acc[c] = half ? 0.f : u[c];
    }

    int start = row_ptr[i], end = row_ptr[i + 1];

    int kk0 = start + half, kk1 = start + 2 + half;
    int s0 = (kk0 < end) ? csr[kk0] : i;
    int s1 = (kk1 < end) ? csr[kk1] : i;
    uint4 ca = *reinterpret_cast<const uint4*>(&xl16[(size_t)s0 * 256 + cb]);
    uint4 cbv = *reinterpret_cast<const uint4*>(&xl16[(size_t)s1 * 256 + cb]);

    for (int k = start; k < end; k += 4) {
        int nk0 = k + 4 + half, nk1 = k + 6 + half;
        int t0 = (nk0 < end) ? csr[nk0] : i;
        int t1 = (nk1 < end) ? csr[nk1] : i;
        uint4 na = *reinterpret_cast<const uint4*>(&xl16[(size_t)t0 * 256 + cb]);
        uint4 nb = *reinterpret_cast<const uint4*>(&xl16[(size_t)t1 * 256 + cb]);

        float ua[8], ub[8];
        h8_to_f(ca, ua);
        h8_to_f(cbv, ub);
        float p0 = 0.f, p1 = 0.f;
        #pragma unroll
        for (int c = 0; c < 8; ++c) {
            float v0 = ua[c] + rxr[c];
            p0 = fmaf(a6[c], v0, p0);
            p0 = fmaf(a4[c], fabsf(v0), p0);
            float v1 = ub[c] + rxr[c];
            p1 = fmaf(a6[c], v1, p1);
            p1 = fmaf(a4[c], fabsf(v1), p1);
        }
        p0 += __shfl_xor(p0, 1, 4);
        p0 += __shfl_xor(p0, 2, 4);
        p1 += __shfl_xor(p1, 1, 4);
        p1 += __shfl_xor(p1, 2, 4);
        float e0 = (k + half < end)     ? __expf(fminf(p0 - m, 60.f)) : 0.f;
        float e1 = (k + 2 + half < end) ? __expf(fminf(p1 - m, 60.f)) : 0.f;
        l += e0 + e1;
        #pragma unroll
        for (int c = 0; c < 8; ++c) acc[c] = fmaf(e0, ua[c], fmaf(e1, ub[c], acc[c]));

        ca = na; cbv = nb;
    }

    l += __shfl_xor(l, 32, 64);
    #pragma unroll
    for (int c = 0; c < 8; ++c) acc[c] += __shfl_xor(acc[c], 32, 64);

    if (half == 0) {
        float4 bb0 = *reinterpret_cast<const float4*>(&bias[cb]);
        float4 bb1 = *reinterpret_cast<const float4*>(&bias[cb + 4]);
        float bs[8] = {bb0.x, bb0.y, bb0.z, bb0.w, bb1.x, bb1.y, bb1.z, bb1.w};
        float inv = 1.0f / l;
        unsigned int hw[4], lw[4];
        #pragma unroll
        for (int c2 = 0; c2 < 4; ++c2) {
            float r0 = fmaf(acc[2 * c2], inv, bs[2 * c2]);
            float r1 = fmaf(acc[2 * c2 + 1], inv, bs[2 * c2 + 1]);
            r0 = (r0 > 0.f) ? r0 : (__expf(r0) - 1.f);
            r1 = (r1 > 0.f) ? r1 : (__expf(r1) - 1.f);
            unsigned short h0 = f2bf_rne(r0), h1 = f2bf_rne(r1);
            float f0 = r0 - __uint_as_float((unsigned int)h0 << 16);
            float f1 = r1 - __uint_as_float((unsigned int)h1 << 16);
            unsigned short l0 = f2bf_rne(f0), l1 = f2bf_rne(f1);
            hw[c2] = (unsigned int)h0 | ((unsigned int)h1 << 16);
            lw[c2] = (unsigned int)l0 | ((unsigned int)l1 << 16);
        }
        *reinterpret_cast<uint4*>(&ohi[(size_t)i * 256 + cb]) = make_uint4(hw[0], hw[1], hw[2], hw[3]);
        *reinterpret_cast<uint4*>(&olo[(size_t)i * 256 + cb]) = make_uint4(lw[0], lw[1], lw[2], lw[3]);
    }
}

// ---------------------------------------------------------------------------
// agg_h1 (layer 3): one wave per node, 8 edge slots x 8 lanes x 8 ch.
// xl gathered as fp16. Fixed-m softmax, 1-deep pipeline.
// ---------------------------------------------------------------------------

__global__ __launch_bounds__(256) void agg_h1_kernel(
    const __half* __restrict__ xl16, const float* __restrict__ xr32,
    const float* __restrict__ att, const float* __restrict__ bias,
    const int* __restrict__ row_ptr, const int* __restrict__ csr,
    float* __restrict__ out, int N) {
    int wv = threadIdx.x >> 6;
    int i = blockIdx.x * 4 + wv;
    if (i >= N) return;
    int lane = threadIdx.x & 63;
    int es = lane >> 3;
    int cb = (lane & 7) * 8;

    float rxr[8], a6[8], a4[8];
    {
        float4 r0 = *reinterpret_cast<const float4*>(&xr32[(size_t)i * 64 + cb]);
        float4 r1 = *reinterpret_cast<const float4*>(&xr32[(size_t)i * 64 + cb + 4]);
        rxr[0] = r0.x; rxr[1] = r0.y; rxr[2] = r0.z; rxr[3] = r0.w;
        rxr[4] = r1.x; rxr[5] = r1.y; rxr[6] = r1.z; rxr[7] = r1.w;
        float4 w0 = *reinterpret_cast<const float4*>(&att[cb]);
        float4 w1 = *reinterpret_cast<const float4*>(&att[cb + 4]);
        float aa[8] = {w0.x, w0.y, w0.z, w0.w, w1.x, w1.y, w1.z, w1.w};
        #pragma unroll
        for (int c = 0; c < 8; ++c) { a6[c] = 0.6f * aa[c]; a4[c] = 0.4f * aa[c]; }
    }

    float acc[8], l, m;
    {
        uint4 sv = *reinterpret_cast<const uint4*>(&xl16[(size_t)i * 64 + cb]);
        float u[8];
        h8_to_f(sv, u);
        float p = 0.f;
        #pragma unroll
        for (int c = 0; c < 8; ++c) {
            float v = u[c] + rxr[c];
            p = fmaf(a6[c], v, p);
            p = fmaf(a4[c], fabsf(v), p);
        }
        p += __shfl_xor(p, 1, 8);
        p += __shfl_xor(p, 2, 8);
        p += __shfl_xor(p, 4, 8);
        m = p;
        l = es ? 0.f : 1.f;
        #pragma unroll
        for (int c = 0; c < 8; ++c) acc[c] = es ? 0.f : u[c];
    }

    int start = row_ptr[i], end = row_ptr[i + 1];

    int kk = start + es;
    int s = (kk < end) ? csr[kk] : i;
    uint4 cu = *reinterpret_cast<const uint4*>(&xl16[(size_t)s * 64 + cb]);

    for (int k = start; k < end; k += 8) {
        int nk = k + 8 + es;
        int tn = (nk < end) ? csr[nk] : i;
        uint4 nu = *reinterpret_cast<const uint4*>(&xl16[(size_t)tn * 64 + cb]);

        float u[8];
        h8_to_f(cu, u);
        float p = 0.f;
        #pragma unroll
        for (int c = 0; c < 8; ++c) {
            float v = u[c] + rxr[c];
            p = fmaf(a6[c], v, p);
            p = fmaf(a4[c], fabsf(v), p);
        }
        p += __shfl_xor(p, 1, 8);
        p += __shfl_xor(p, 2, 8);
        p += __shfl_xor(p, 4, 8);
        float e = (k + es < end) ? __expf(fminf(p - m, 60.f)) : 0.f;
        l += e;
        #pragma unroll
        for (int c = 0; c < 8; ++c) acc[c] = fmaf(e, u[c], acc[c]);

        cu = nu;
    }

    l += __shfl_xor(l, 8, 64);
    l += __shfl_xor(l, 16, 64);
    l += __shfl_xor(l, 32, 64);
    #pragma unroll
    for (int c = 0; c < 8; ++c) {
        acc[c] += __shfl_xor(acc[c], 8, 64);
        acc[c] += __shfl_xor(acc[c], 16, 64);
        acc[c] += __shfl_xor(acc[c], 32, 64);
    }

    if (es == 0) {
        float inv = 1.0f / l;
        float4 bb0 = *reinterpret_cast<const float4*>(&bias[cb]);
        float4 bb1 = *reinterpret_cast<const float4*>(&bias[cb + 4]);
        float4 o0, o1;
        o0.x = fmaf(acc[0], inv, bb0.x);
        o0.y = fmaf(acc[1], inv, bb0.y);
        o0.z = fmaf(acc[2], inv, bb0.z);
        o0.w = fmaf(acc[3], inv, bb0.w);
        o1.x = fmaf(acc[4], inv, bb1.x);
        o1.y = fmaf(acc[5], inv, bb1.y);
        o1.z = fmaf(acc[6], inv, bb1.z);
        o1.w = fmaf(acc[7], inv, bb1.w);
        *reinterpret_cast<float4*>(&out[(size_t)i * 64 + cb]) = o0;
        *reinterpret_cast<float4*>(&out[(size_t)i * 64 + cb + 4]) = o1;
    }
}

// ---------------------------------------------------------------------------

extern "C" void kernel_launch(void* const* d_in, const int* in_sizes, int n_in,
                              void* d_out, int out_size, void* d_ws, size_t ws_size,
                              hipStream_t stream) {
    const float* x    = (const float*)d_in[0];
    const void*  ei   = d_in[1];
    const float* Wl1  = (const float*)d_in[2];
    const float* Wr1  = (const float*)d_in[3];
    const float* att1 = (const float*)d_in[4];
    const float* b1   = (const float*)d_in[5];
    const float* Wl2  = (const float*)d_in[6];
    const float* Wr2  = (const float*)d_in[7];
    const float* att2 = (const float*)d_in[8];
    const float* b2   = (const float*)d_in[9];
    const float* Wl3  = (const float*)d_in[10];
    const float* Wr3  = (const float*)d_in[11];
    const float* att3 = (const float*)d_in[12];
    const float* b3   = (const float*)d_in[13];
    float* out = (float*)d_out;

    int N = in_sizes[0] / 256;
    int E = in_sizes[1] / 2;

    char* w = (char*)d_ws;
    unsigned short* h_hi = (unsigned short*)w; w += (size_t)N * 256 * 2;
    unsigned short* h_lo = (unsigned short*)w; w += (size_t)N * 256 * 2;
    __half* xl16 = (__half*)w;     w += (size_t)N * 256 * 2;
    float* xr32 = (float*)w;       w += (size_t)N * 256 * sizeof(float);
    unsigned short* WT_hi = (unsigned short*)w; w += (size_t)512 * 256 * 2;
    unsigned short* WT_lo = (unsigned short*)w; w += (size_t)512 * 256 * 2;
    int* row_ptr = (int*)w; w += ((size_t)N + 2) * sizeof(int);
    int* deg     = (int*)w; w += (size_t)N * sizeof(int);
    int* csr     = (int*)w; w += (size_t)E * sizeof(int);
    int* flag    = (int*)w; w += 256;
    int* partial = (int*)w; w += 256;

    // --- CSR build ---
    detect_i64_kernel<<<1, 256, 0, stream>>>((const unsigned int*)ei, E, flag);
    hipMemsetAsync(deg, 0, (size_t)N * sizeof(int), stream);
    count_deg_kernel<<<(E + 255) / 256, 256, 0, stream>>>(ei, E, flag, deg);
    int nb = (N + 1023) / 1024;
    scan_block_kernel<<<nb, 1024, 0, stream>>>(deg, row_ptr, partial, N);
    scan_top_kernel<<<1, 64, 0, stream>>>(partial, nb);
    scan_addoff_kernel<<<(N + 255) / 256, 256, 0, stream>>>(row_ptr, partial, N);
    hipMemsetAsync(deg, 0, (size_t)N * sizeof(int), stream);
    scatter_kernel<<<(E + 255) / 256, 256, 0, stream>>>(ei, E, flag, row_ptr, deg, csr);

    int gemm_gx = (N + 127) / 128;
    int agg_g = (N + 3) / 4;

    // --- Layer 1 ---
    split_kernel<<<((N * 256 / 4) + 255) / 256, 256, 0, stream>>>(x, N * 256 / 4, h_hi, h_lo);
    splitT_w_kernel<<<dim3(256, 2), 256, 0, stream>>>(Wl1, Wr1, 256, WT_hi, WT_lo);
    gemm_mfma_kernel<<<dim3(gemm_gx, 4), 256, 0, stream>>>(h_hi, h_lo, WT_hi, WT_lo, xl16, xr32, N, 256);
    agg_h8_kernel<<<agg_g, 256, 0, stream>>>(xl16, xr32, att1, b1, row_ptr, csr, h_hi, h_lo, N);

    // --- Layer 2 ---
    splitT_w_kernel<<<dim3(256, 2), 256, 0, stream>>>(Wl2, Wr2, 256, WT_hi, WT_lo);
    gemm_mfma_kernel<<<dim3(gemm_gx, 4), 256, 0, stream>>>(h_hi, h_lo, WT_hi, WT_lo, xl16, xr32, N, 256);
    agg_h8_kernel<<<agg_g, 256, 0, stream>>>(xl16, xr32, att2, b2, row_ptr, csr, h_hi, h_lo, N);

    // --- Layer 3 ---
    splitT_w_kernel<<<dim3(256, 1), 256, 0, stream>>>(Wl3, Wr3, 64, WT_hi, WT_lo);
    gemm_mfma_kernel<<<dim3(gemm_gx, 1), 256, 0, stream>>>(h_hi, h_lo, WT_hi, WT_lo, xl16, xr32, N, 64);
    agg_h1_kernel<<<agg_g, 256, 0, stream>>>(xl16, xr32, att3, b3, row_ptr, csr, out, N);
}

// Round 10
// 482.812 us; speedup vs baseline: 1.1310x; 1.1310x over previous
//
#include <hip/hip_runtime.h>
#include <hip/hip_fp16.h>

#define NEG_SLOPE 0.2f

typedef __attribute__((ext_vector_type(8))) short bf16x8;
typedef __attribute__((ext_vector_type(4))) float f32x4;

__device__ __forceinline__ unsigned short f2bf_rne(float x) {
    unsigned int u = __float_as_uint(x);
    unsigned int r = (u + 0x7FFFu + ((u >> 16) & 1u)) >> 16;
    return (unsigned short)r;
}

__device__ __forceinline__ void gload_lds16(const unsigned short* g, unsigned short* lds) {
    __builtin_amdgcn_global_load_lds(
        (const __attribute__((address_space(1))) void*)g,
        (__attribute__((address_space(3))) void*)lds, 16, 0, 0);
}

__device__ __forceinline__ void h8_to_f(const uint4 v, float* f) {
    const __half2* hp = reinterpret_cast<const __half2*>(&v);
    float2 t0 = __half22float2(hp[0]);
    float2 t1 = __half22float2(hp[1]);
    float2 t2 = __half22float2(hp[2]);
    float2 t3 = __half22float2(hp[3]);
    f[0] = t0.x; f[1] = t0.y; f[2] = t1.x; f[3] = t1.y;
    f[4] = t2.x; f[5] = t2.y; f[6] = t3.x; f[7] = t3.y;
}

// ---------------------------------------------------------------------------
// CSR build
// ---------------------------------------------------------------------------

__global__ void detect_i64_kernel(const unsigned int* __restrict__ w, int E, int* __restrict__ flag) {
    __shared__ unsigned int ssum[256];
    int n = E < 4096 ? E : 4096;
    unsigned int local = 0;
    for (int k = threadIdx.x; k < n; k += 256) local |= w[2 * k + 1];
    ssum[threadIdx.x] = local;
    __syncthreads();
    for (int off = 128; off > 0; off >>= 1) {
        if (threadIdx.x < off) ssum[threadIdx.x] |= ssum[threadIdx.x + off];
        __syncthreads();
    }
    if (threadIdx.x == 0) flag[0] = (ssum[0] == 0) ? 1 : 0;
}

__global__ void count_deg_kernel(const void* __restrict__ eiv, int E,
                                 const int* __restrict__ flag, int* __restrict__ deg) {
    int e = blockIdx.x * blockDim.x + threadIdx.x;
    if (e >= E) return;
    int d;
    if (*flag) d = (int)((const long long*)eiv)[(size_t)E + e];
    else       d = ((const int*)eiv)[(size_t)E + e];
    atomicAdd(&deg[d], 1);
}

__global__ void scan_block_kernel(const int* __restrict__ deg, int* __restrict__ row_ptr,
                                  int* __restrict__ partial, int N) {
    __shared__ int sd[1024];
    int t = threadIdx.x;
    int g = blockIdx.x * 1024 + t;
    int v = (g < N) ? deg[g] : 0;
    sd[t] = v;
    __syncthreads();
    for (int off = 1; off < 1024; off <<= 1) {
        int add = (t >= off) ? sd[t - off] : 0;
        __syncthreads();
        sd[t] += add;
        __syncthreads();
    }
    if (g < N) row_ptr[g + 1] = sd[t];
    if (t == 1023) partial[blockIdx.x] = sd[1023];
    if (g == 0) row_ptr[0] = 0;
}

__global__ void scan_top_kernel(int* __restrict__ partial, int nb) {
    if (threadIdx.x == 0 && blockIdx.x == 0) {
        int run = 0;
        for (int j = 0; j < nb; ++j) { run += partial[j]; partial[j] = run; }
    }
}

__global__ void scan_addoff_kernel(int* __restrict__ row_ptr, const int* __restrict__ partial, int N) {
    int g = blockIdx.x * 256 + threadIdx.x;
    if (g >= N) return;
    int b = g >> 10;
    if (b > 0) row_ptr[g + 1] += partial[b - 1];
}

__global__ void scatter_kernel(const void* __restrict__ eiv, int E,
                               const int* __restrict__ flag,
                               const int* __restrict__ row_ptr,
                               int* __restrict__ cursor, int* __restrict__ csr) {
    int e = blockIdx.x * blockDim.x + threadIdx.x;
    if (e >= E) return;
    int s, d;
    if (*flag) {
        s = (int)((const long long*)eiv)[e];
        d = (int)((const long long*)eiv)[(size_t)E + e];
    } else {
        s = ((const int*)eiv)[e];
        d = ((const int*)eiv)[(size_t)E + e];
    }
    int pos = atomicAdd(&cursor[d], 1);
    csr[row_ptr[d] + pos] = s;
}

// ---------------------------------------------------------------------------
// fp32 -> bf16 hi/lo split
// ---------------------------------------------------------------------------

__global__ void split_kernel(const float* __restrict__ src, int n4,
                             unsigned short* __restrict__ hi, unsigned short* __restrict__ lo) {
    int i = blockIdx.x * blockDim.x + threadIdx.x;
    if (i >= n4) return;
    float4 v = *reinterpret_cast<const float4*>(&src[(size_t)i * 4]);
    ushort4 h, l;
    float f;
    h.x = f2bf_rne(v.x); f = v.x - __uint_as_float((unsigned int)h.x << 16); l.x = f2bf_rne(f);
    h.y = f2bf_rne(v.y); f = v.y - __uint_as_float((unsigned int)h.y << 16); l.y = f2bf_rne(f);
    h.z = f2bf_rne(v.z); f = v.z - __uint_as_float((unsigned int)h.z << 16); l.z = f2bf_rne(f);
    h.w = f2bf_rne(v.w); f = v.w - __uint_as_float((unsigned int)h.w << 16); l.w = f2bf_rne(f);
    *reinterpret_cast<ushort4*>(&hi[(size_t)i * 4]) = h;
    *reinterpret_cast<ushort4*>(&lo[(size_t)i * 4]) = l;
}

__global__ void splitT_w_kernel(const float* __restrict__ Wl, const float* __restrict__ Wr, int M,
                                unsigned short* __restrict__ WThi, unsigned short* __restrict__ WTlo) {
    int k = blockIdx.x;
    int m2 = blockIdx.y * 256 + threadIdx.x;
    if (m2 >= 2 * M) return;
    float v = (m2 < M) ? Wl[(size_t)k * M + m2] : Wr[(size_t)k * M + (m2 - M)];
    unsigned short h = f2bf_rne(v);
    float fl = v - __uint_as_float((unsigned int)h << 16);
    WThi[(size_t)m2 * 256 + k] = h;
    WTlo[(size_t)m2 * 256 + k] = f2bf_rne(fl);
}

// ---------------------------------------------------------------------------
// MFMA GEMM: split-bf16 flattened to ONE plain bf16 GEMM over extended K=768.
// Steps 0-3: Ahi x Bhi; 4-7: Ahi x Blo; 8-11: Alo x Bhi (wave-uniform pointer
// select; re-reads are L2 hits). Tile 128x128, BK=64, single-buffered 32 KB
// LDS (sA+sB), gload_lds staging with pre-swizzled global source (R7-proven).
// Epilogue: cols [0,M) -> fp16 xl buffer; cols [M,2M) -> fp32 xr buffer.
// ---------------------------------------------------------------------------

__global__ __launch_bounds__(256) void gemm_mfma_kernel(
    const unsigned short* __restrict__ Ahi, const unsigned short* __restrict__ Alo,
    const unsigned short* __restrict__ Bhi, const unsigned short* __restrict__ Blo,
    __half* __restrict__ xl16, float* __restrict__ xr32, int N, int M) {
    __shared__ unsigned short sA[128 * 64];
    __shared__ unsigned short sB[128 * 64];

    int t = threadIdx.x;
    int lane = t & 63;
    int w = t >> 6;
    int wr = (w >> 1) * 64;
    int wc = (w & 1) * 64;
    int row0 = blockIdx.x * 128;
    int n0 = blockIdx.y * 128;

    int l15 = lane & 15;
    int l4 = lane >> 4;

    int lr8 = lane >> 3;
    int lc8 = lane & 7;
    int ksw = (lc8 ^ lr8) * 8;

    f32x4 acc[4][4] = {};

    for (int step = 0; step < 12; ++step) {
        const unsigned short* pA = (step < 8) ? Ahi : Alo;
        const unsigned short* pB = (step >= 4 && step < 8) ? Blo : Bhi;
        int k0 = (step & 3) * 64;

        __syncthreads();
        #pragma unroll
        for (int i = 0; i < 4; ++i) {
            int brow = i * 32 + w * 8;
            int row = brow + lr8;
            int ar = row0 + row; if (ar >= N) ar = N - 1;
            int bc = n0 + row;
            gload_lds16(&pA[(size_t)ar * 256 + k0 + ksw], &sA[brow * 64]);
            gload_lds16(&pB[(size_t)bc * 256 + k0 + ksw], &sB[brow * 64]);
        }
        __syncthreads();

        #pragma unroll
        for (int ksub = 0; ksub < 2; ++ksub) {
            int kb = ksub * 32 + l4 * 8;
            bf16x8 b[4];
            #pragma unroll
            for (int fc = 0; fc < 4; ++fc) {
                int cc = wc + fc * 16 + l15;
                b[fc] = *reinterpret_cast<const bf16x8*>(&sB[cc * 64 + (kb ^ ((cc & 7) << 3))]);
            }
            #pragma unroll
            for (int fr = 0; fr < 4; ++fr) {
                int r = wr + fr * 16 + l15;
                bf16x8 a = *reinterpret_cast<const bf16x8*>(&sA[r * 64 + (kb ^ ((r & 7) << 3))]);
                #pragma unroll
                for (int fc = 0; fc < 4; ++fc) {
                    acc[fr][fc] = __builtin_amdgcn_mfma_f32_16x16x32_bf16(a, b[fc], acc[fr][fc], 0, 0, 0);
                }
            }
        }
    }

    #pragma unroll
    for (int fr = 0; fr < 4; ++fr) {
        #pragma unroll
        for (int j = 0; j < 4; ++j) {
            int row = row0 + wr + fr * 16 + l4 * 4 + j;
            if (row < N) {
                #pragma unroll
                for (int fc = 0; fc < 4; ++fc) {
                    int col = n0 + wc + fc * 16 + l15;
                    float v = acc[fr][fc][j];
                    if (col < M) xl16[(size_t)row * M + col] = __float2half(v);
                    else         xr32[(size_t)row * M + (col - M)] = v;
                }
            }
        }
    }
}

// ---------------------------------------------------------------------------
// agg_h8: one wave per node; half = lane>>5 picks edge slot, lane&31 owns
// 8 channels. xl gathered as fp16 (one 16B load/lane/edge); xr read fp32 once.
// Fixed-m softmax (m = self logit), 1-deep pipeline.
// ---------------------------------------------------------------------------

__global__ __launch_bounds__(256) void agg_h8_kernel(
    const __half* __restrict__ xl16, const float* __restrict__ xr32,
    const float* __restrict__ att, const float* __restrict__ bias,
    const int* __restrict__ row_ptr, const int* __restrict__ csr,
    unsigned short* __restrict__ ohi, unsigned short* __restrict__ olo, int N) {
    int wv = threadIdx.x >> 6;
    int i = blockIdx.x * 4 + wv;
    if (i >= N) return;
    int lane = threadIdx.x & 63;
    int half = lane >> 5;
    int cb = (lane & 31) * 8;

    float rxr[8], a6[8], a4[8];
    {
        float4 r0 = *reinterpret_cast<const float4*>(&xr32[(size_t)i * 256 + cb]);
        float4 r1 = *reinterpret_cast<const float4*>(&xr32[(size_t)i * 256 + cb + 4]);
        rxr[0] = r0.x; rxr[1] = r0.y; rxr[2] = r0.z; rxr[3] = r0.w;
        rxr[4] = r1.x; rxr[5] = r1.y; rxr[6] = r1.z; rxr[7] = r1.w;
        float4 w0 = *reinterpret_cast<const float4*>(&att[cb]);
        float4 w1 = *reinterpret_cast<const float4*>(&att[cb + 4]);
        float aa[8] = {w0.x, w0.y, w0.z, w0.w, w1.x, w1.y, w1.z, w1.w};
        #pragma unroll
        for (int c = 0; c < 8; ++c) { a6[c] = 0.6f * aa[c]; a4[c] = 0.4f * aa[c]; }
    }

    float acc[8], l, m;
    {
        uint4 sv = *reinterpret_cast<const uint4*>(&xl16[(size_t)i * 256 + cb]);
        float u[8];
        h8_to_f(sv, u);
        float p = 0.f;
        #pragma unroll
        for (int c = 0; c < 8; ++c) {
            float v = u[c] + rxr[c];
            p = fmaf(a6[c], v, p);
            p = fmaf(a4[c], fabsf(v), p);
        }
        p += __shfl_xor(p, 1, 4);
        p += __shfl_xor(p, 2, 4);
        m = p;
        l = half ? 0.f : 1.f;
        #pragma unroll
        for (int c = 0; c < 8; ++c) acc[c] = half ? 0.f : u[c];
    }

    int start = row_ptr[i], end = row_ptr[i + 1];

    int kk0 = start + half, kk1 = start + 2 + half;
    int s0 = (kk0 < end) ? csr[kk0] : i;
    int s1 = (kk1 < end) ? csr[kk1] : i;
    uint4 ca = *reinterpret_cast<const uint4*>(&xl16[(size_t)s0 * 256 + cb]);
    uint4 cbv = *reinterpret_cast<const uint4*>(&xl16[(size_t)s1 * 256 + cb]);

    for (int k = start; k < end; k += 4) {
        int nk0 = k + 4 + half, nk1 = k + 6 + half;
        int t0 = (nk0 < end) ? csr[nk0] : i;
        int t1 = (nk1 < end) ? csr[nk1] : i;
        uint4 na = *reinterpret_cast<const uint4*>(&xl16[(size_t)t0 * 256 + cb]);
        uint4 nb = *reinterpret_cast<const uint4*>(&xl16[(size_t)t1 * 256 + cb]);

        float ua[8], ub[8];
        h8_to_f(ca, ua);
        h8_to_f(cbv, ub);
        float p0 = 0.f, p1 = 0.f;
        #pragma unroll
        for (int c = 0; c < 8; ++c) {
            float v0 = ua[c] + rxr[c];
            p0 = fmaf(a6[c], v0, p0);
            p0 = fmaf(a4[c], fabsf(v0), p0);
            float v1 = ub[c] + rxr[c];
            p1 = fmaf(a6[c], v1, p1);
            p1 = fmaf(a4[c], fabsf(v1), p1);
        }
        p0 += __shfl_xor(p0, 1, 4);
        p0 += __shfl_xor(p0, 2, 4);
        p1 += __shfl_xor(p1, 1, 4);
        p1 += __shfl_xor(p1, 2, 4);
        float e0 = (k + half < end)     ? __expf(fminf(p0 - m, 60.f)) : 0.f;
        float e1 = (k + 2 + half < end) ? __expf(fminf(p1 - m, 60.f)) : 0.f;
        l += e0 + e1;
        #pragma unroll
        for (int c = 0; c < 8; ++c) acc[c] = fmaf(e0, ua[c], fmaf(e1, ub[c], acc[c]));

        ca = na; cbv = nb;
    }

    l += __shfl_xor(l, 32, 64);
    #pragma unroll
    for (int c = 0; c < 8; ++c) acc[c] += __shfl_xor(acc[c], 32, 64);

    if (half == 0) {
        float4 bb0 = *reinterpret_cast<const float4*>(&bias[cb]);
        float4 bb1 = *reinterpret_cast<const float4*>(&bias[cb + 4]);
        float bs[8] = {bb0.x, bb0.y, bb0.z, bb0.w, bb1.x, bb1.y, bb1.z, bb1.w};
        float inv = 1.0f / l;
        unsigned int hw[4], lw[4];
        #pragma unroll
        for (int c2 = 0; c2 < 4; ++c2) {
            float r0 = fmaf(acc[2 * c2], inv, bs[2 * c2]);
            float r1 = fmaf(acc[2 * c2 + 1], inv, bs[2 * c2 + 1]);
            r0 = (r0 > 0.f) ? r0 : (__expf(r0) - 1.f);
            r1 = (r1 > 0.f) ? r1 : (__expf(r1) - 1.f);
            unsigned short h0 = f2bf_rne(r0), h1 = f2bf_rne(r1);
            float f0 = r0 - __uint_as_float((unsigned int)h0 << 16);
            float f1 = r1 - __uint_as_float((unsigned int)h1 << 16);
            unsigned short l0 = f2bf_rne(f0), l1 = f2bf_rne(f1);
            hw[c2] = (unsigned int)h0 | ((unsigned int)h1 << 16);
            lw[c2] = (unsigned int)l0 | ((unsigned int)l1 << 16);
        }
        *reinterpret_cast<uint4*>(&ohi[(size_t)i * 256 + cb]) = make_uint4(hw[0], hw[1], hw[2], hw[3]);
        *reinterpret_cast<uint4*>(&olo[(size_t)i * 256 + cb]) = make_uint4(lw[0], lw[1], lw[2], lw[3]);
    }
}

// ---------------------------------------------------------------------------
// agg_h1 (layer 3): one wave per node, 8 edge slots x 8 lanes x 8 ch.
// xl gathered as fp16. Fixed-m softmax, 1-deep pipeline.
// ---------------------------------------------------------------------------

__global__ __launch_bounds__(256) void agg_h1_kernel(
    const __half* __restrict__ xl16, const float* __restrict__ xr32,
    const float* __restrict__ att, const float* __restrict__ bias,
    const int* __restrict__ row_ptr, const int* __restrict__ csr,
    float* __restrict__ out, int N) {
    int wv = threadIdx.x >> 6;
    int i = blockIdx.x * 4 + wv;
    if (i >= N) return;
    int lane = threadIdx.x & 63;
    int es = lane >> 3;
    int cb = (lane & 7) * 8;

    float rxr[8], a6[8], a4[8];
    {
        float4 r0 = *reinterpret_cast<const float4*>(&xr32[(size_t)i * 64 + cb]);
        float4 r1 = *reinterpret_cast<const float4*>(&xr32[(size_t)i * 64 + cb + 4]);
        rxr[0] = r0.x; rxr[1] = r0.y; rxr[2] = r0.z; rxr[3] = r0.w;
        rxr[4] = r1.x; rxr[5] = r1.y; rxr[6] = r1.z; rxr[7] = r1.w;
        float4 w0 = *reinterpret_cast<const float4*>(&att[cb]);
        float4 w1 = *reinterpret_cast<const float4*>(&att[cb + 4]);
        float aa[8] = {w0.x, w0.y, w0.z, w0.w, w1.x, w1.y, w1.z, w1.w};
        #pragma unroll
        for (int c = 0; c < 8; ++c) { a6[c] = 0.6f * aa[c]; a4[c] = 0.4f * aa[c]; }
    }

    float acc[8], l, m;
    {
        uint4 sv = *reinterpret_cast<const uint4*>(&xl16[(size_t)i * 64 + cb]);
        float u[8];
        h8_to_f(sv, u);
        float p = 0.f;
        #pragma unroll
        for (int c = 0; c < 8; ++c) {
            float v = u[c] + rxr[c];
            p = fmaf(a6[c], v, p);
            p = fmaf(a4[c], fabsf(v), p);
        }
        p += __shfl_xor(p, 1, 8);
        p += __shfl_xor(p, 2, 8);
        p += __shfl_xor(p, 4, 8);
        m = p;
        l = es ? 0.f : 1.f;
        #pragma unroll
        for (int c = 0; c < 8; ++c) acc[c] = es ? 0.f : u[c];
    }

    int start = row_ptr[i], end = row_ptr[i + 1];

    int kk = start + es;
    int s = (kk < end) ? csr[kk] : i;
    uint4 cu = *reinterpret_cast<const uint4*>(&xl16[(size_t)s * 64 + cb]);

    for (int k = start; k < end; k += 8) {
        int nk = k + 8 + es;
        int tn = (nk < end) ? csr[nk] : i;
        uint4 nu = *reinterpret_cast<const uint4*>(&xl16[(size_t)tn * 64 + cb]);

        float u[8];
        h8_to_f(cu, u);
        float p = 0.f;
        #pragma unroll
        for (int c = 0; c < 8; ++c) {
            float v = u[c] + rxr[c];
            p = fmaf(a6[c], v, p);
            p = fmaf(a4[c], fabsf(v), p);
        }
        p += __shfl_xor(p, 1, 8);
        p += __shfl_xor(p, 2, 8);
        p += __shfl_xor(p, 4, 8);
        float e = (k + es < end) ? __expf(fminf(p - m, 60.f)) : 0.f;
        l += e;
        #pragma unroll
        for (int c = 0; c < 8; ++c) acc[c] = fmaf(e, u[c], acc[c]);

        cu = nu;
    }

    l += __shfl_xor(l, 8, 64);
    l += __shfl_xor(l, 16, 64);
    l += __shfl_xor(l, 32, 64);
    #pragma unroll
    for (int c = 0; c < 8; ++c) {
        acc[c] += __shfl_xor(acc[c], 8, 64);
        acc[c] += __shfl_xor(acc[c], 16, 64);
        acc[c] += __shfl_xor(acc[c], 32, 64);
    }

    if (es == 0) {
        float inv = 1.0f / l;
        float4 bb0 = *reinterpret_cast<const float4*>(&bias[cb]);
        float4 bb1 = *reinterpret_cast<const float4*>(&bias[cb + 4]);
        float4 o0, o1;
        o0.x = fmaf(acc[0], inv, bb0.x);
        o0.y = fmaf(acc[1], inv, bb0.y);
        o0.z = fmaf(acc[2], inv, bb0.z);
        o0.w = fmaf(acc[3], inv, bb0.w);
        o1.x = fmaf(acc[4], inv, bb1.x);
        o1.y = fmaf(acc[5], inv, bb1.y);
        o1.z = fmaf(acc[6], inv, bb1.z);
        o1.w = fmaf(acc[7], inv, bb1.w);
        *reinterpret_cast<float4*>(&out[(size_t)i * 64 + cb]) = o0;
        *reinterpret_cast<float4*>(&out[(size_t)i * 64 + cb + 4]) = o1;
    }
}

// ---------------------------------------------------------------------------

extern "C" void kernel_launch(void* const* d_in, const int* in_sizes, int n_in,
                              void* d_out, int out_size, void* d_ws, size_t ws_size,
                              hipStream_t stream) {
    const float* x    = (const float*)d_in[0];
    const void*  ei   = d_in[1];
    const float* Wl1  = (const float*)d_in[2];
    const float* Wr1  = (const float*)d_in[3];
    const float* att1 = (const float*)d_in[4];
    const float* b1   = (const float*)d_in[5];
    const float* Wl2  = (const float*)d_in[6];
    const float* Wr2  = (const float*)d_in[7];
    const float* att2 = (const float*)d_in[8];
    const float* b2   = (const float*)d_in[9];
    const float* Wl3  = (const float*)d_in[10];
    const float* Wr3  = (const float*)d_in[11];
    const float* att3 = (const float*)d_in[12];
    const float* b3   = (const float*)d_in[13];
    float* out = (float*)d_out;

    int N = in_sizes[0] / 256;
    int E = in_sizes[1] / 2;

    char* w = (char*)d_ws;
    unsigned short* h_hi = (unsigned short*)w; w += (size_t)N * 256 * 2;
    unsigned short* h_lo = (unsigned short*)w; w += (size_t)N * 256 * 2;
    __half* xl16 = (__half*)w;     w += (size_t)N * 256 * 2;
    float* xr32 = (float*)w;       w += (size_t)N * 256 * sizeof(float);
    unsigned short* WT_hi = (unsigned short*)w; w += (size_t)512 * 256 * 2;
    unsigned short* WT_lo = (unsigned short*)w; w += (size_t)512 * 256 * 2;
    int* row_ptr = (int*)w; w += ((size_t)N + 2) * sizeof(int);
    int* deg     = (int*)w; w += (size_t)N * sizeof(int);
    int* csr     = (int*)w; w += (size_t)E * sizeof(int);
    int* flag    = (int*)w; w += 256;
    int* partial = (int*)w; w += 256;

    // --- CSR build ---
    detect_i64_kernel<<<1, 256, 0, stream>>>((const unsigned int*)ei, E, flag);
    hipMemsetAsync(deg, 0, (size_t)N * sizeof(int), stream);
    count_deg_kernel<<<(E + 255) / 256, 256, 0, stream>>>(ei, E, flag, deg);
    int nb = (N + 1023) / 1024;
    scan_block_kernel<<<nb, 1024, 0, stream>>>(deg, row_ptr, partial, N);
    scan_top_kernel<<<1, 64, 0, stream>>>(partial, nb);
    scan_addoff_kernel<<<(N + 255) / 256, 256, 0, stream>>>(row_ptr, partial, N);
    hipMemsetAsync(deg, 0, (size_t)N * sizeof(int), stream);
    scatter_kernel<<<(E + 255) / 256, 256, 0, stream>>>(ei, E, flag, row_ptr, deg, csr);

    int gemm_gx = (N + 127) / 128;
    int agg_g = (N + 3) / 4;

    // --- Layer 1 ---
    split_kernel<<<((N * 256 / 4) + 255) / 256, 256, 0, stream>>>(x, N * 256 / 4, h_hi, h_lo);
    splitT_w_kernel<<<dim3(256, 2), 256, 0, stream>>>(Wl1, Wr1, 256, WT_hi, WT_lo);
    gemm_mfma_kernel<<<dim3(gemm_gx, 4), 256, 0, stream>>>(h_hi, h_lo, WT_hi, WT_lo, xl16, xr32, N, 256);
    agg_h8_kernel<<<agg_g, 256, 0, stream>>>(xl16, xr32, att1, b1, row_ptr, csr, h_hi, h_lo, N);

    // --- Layer 2 ---
    splitT_w_kernel<<<dim3(256, 2), 256, 0, stream>>>(Wl2, Wr2, 256, WT_hi, WT_lo);
    gemm_mfma_kernel<<<dim3(gemm_gx, 4), 256, 0, stream>>>(h_hi, h_lo, WT_hi, WT_lo, xl16, xr32, N, 256);
    agg_h8_kernel<<<agg_g, 256, 0, stream>>>(xl16, xr32, att2, b2, row_ptr, csr, h_hi, h_lo, N);

    // --- Layer 3 ---
    splitT_w_kernel<<<dim3(256, 1), 256, 0, stream>>>(Wl3, Wr3, 64, WT_hi, WT_lo);
    gemm_mfma_kernel<<<dim3(gemm_gx, 1), 256, 0, stream>>>(h_hi, h_lo, WT_hi, WT_lo, xl16, xr32, N, 64);
    agg_h1_kernel<<<agg_g, 256, 0, stream>>>(xl16, xr32, att3, b3, row_ptr, csr, out, N);
}

// Round 11
// 413.160 us; speedup vs baseline: 1.3216x; 1.1686x over previous
//
#include <hip/hip_runtime.h>
#include <hip/hip_fp16.h>

#define NEG_SLOPE 0.2f

typedef __attribute__((ext_vector_type(8))) _Float16 f16x8;
typedef __attribute__((ext_vector_type(4))) float f32x4;

__device__ __forceinline__ void gload_lds16(const unsigned short* g, unsigned short* lds) {
    __builtin_amdgcn_global_load_lds(
        (const __attribute__((address_space(1))) void*)g,
        (__attribute__((address_space(3))) void*)lds, 16, 0, 0);
}

__device__ __forceinline__ void h8_to_f(const uint4 v, float* f) {
    const __half2* hp = reinterpret_cast<const __half2*>(&v);
    float2 t0 = __half22float2(hp[0]);
    float2 t1 = __half22float2(hp[1]);
    float2 t2 = __half22float2(hp[2]);
    float2 t3 = __half22float2(hp[3]);
    f[0] = t0.x; f[1] = t0.y; f[2] = t1.x; f[3] = t1.y;
    f[4] = t2.x; f[5] = t2.y; f[6] = t3.x; f[7] = t3.y;
}

// ---------------------------------------------------------------------------
// CSR build
// ---------------------------------------------------------------------------

__global__ void detect_i64_kernel(const unsigned int* __restrict__ w, int E, int* __restrict__ flag) {
    __shared__ unsigned int ssum[256];
    int n = E < 4096 ? E : 4096;
    unsigned int local = 0;
    for (int k = threadIdx.x; k < n; k += 256) local |= w[2 * k + 1];
    ssum[threadIdx.x] = local;
    __syncthreads();
    for (int off = 128; off > 0; off >>= 1) {
        if (threadIdx.x < off) ssum[threadIdx.x] |= ssum[threadIdx.x + off];
        __syncthreads();
    }
    if (threadIdx.x == 0) flag[0] = (ssum[0] == 0) ? 1 : 0;
}

__global__ void count_deg_kernel(const void* __restrict__ eiv, int E,
                                 const int* __restrict__ flag, int* __restrict__ deg) {
    int e = blockIdx.x * blockDim.x + threadIdx.x;
    if (e >= E) return;
    int d;
    if (*flag) d = (int)((const long long*)eiv)[(size_t)E + e];
    else       d = ((const int*)eiv)[(size_t)E + e];
    atomicAdd(&deg[d], 1);
}

__global__ void scan_block_kernel(const int* __restrict__ deg, int* __restrict__ row_ptr,
                                  int* __restrict__ partial, int N) {
    __shared__ int sd[1024];
    int t = threadIdx.x;
    int g = blockIdx.x * 1024 + t;
    int v = (g < N) ? deg[g] : 0;
    sd[t] = v;
    __syncthreads();
    for (int off = 1; off < 1024; off <<= 1) {
        int add = (t >= off) ? sd[t - off] : 0;
        __syncthreads();
        sd[t] += add;
        __syncthreads();
    }
    if (g < N) row_ptr[g + 1] = sd[t];
    if (t == 1023) partial[blockIdx.x] = sd[1023];
    if (g == 0) row_ptr[0] = 0;
}

__global__ void scan_top_kernel(int* __restrict__ partial, int nb) {
    if (threadIdx.x == 0 && blockIdx.x == 0) {
        int run = 0;
        for (int j = 0; j < nb; ++j) { run += partial[j]; partial[j] = run; }
    }
}

__global__ void scan_addoff_kernel(int* __restrict__ row_ptr, const int* __restrict__ partial, int N) {
    int g = blockIdx.x * 256 + threadIdx.x;
    if (g >= N) return;
    int b = g >> 10;
    if (b > 0) row_ptr[g + 1] += partial[b - 1];
}

__global__ void scatter_kernel(const void* __restrict__ eiv, int E,
                               const int* __restrict__ flag,
                               const int* __restrict__ row_ptr,
                               int* __restrict__ cursor, int* __restrict__ csr) {
    int e = blockIdx.x * blockDim.x + threadIdx.x;
    if (e >= E) return;
    int s, d;
    if (*flag) {
        s = (int)((const long long*)eiv)[e];
        d = (int)((const long long*)eiv)[(size_t)E + e];
    } else {
        s = ((const int*)eiv)[e];
        d = ((const int*)eiv)[(size_t)E + e];
    }
    int pos = atomicAdd(&cursor[d], 1);
    csr[row_ptr[d] + pos] = s;
}

// ---------------------------------------------------------------------------
// fp32 -> fp16 hi/lo split (A operand); weights -> plain fp16 (B operand)
// ---------------------------------------------------------------------------

__global__ void split_kernel(const float* __restrict__ src, int n4,
                             unsigned short* __restrict__ hi, unsigned short* __restrict__ lo) {
    int i = blockIdx.x * blockDim.x + threadIdx.x;
    if (i >= n4) return;
    float4 v = *reinterpret_cast<const float4*>(&src[(size_t)i * 4]);
    ushort4 h, l;
    __half t;
    t = __float2half(v.x); h.x = __half_as_ushort(t); l.x = __half_as_ushort(__float2half(v.x - __half2float(t)));
    t = __float2half(v.y); h.y = __half_as_ushort(t); l.y = __half_as_ushort(__float2half(v.y - __half2float(t)));
    t = __float2half(v.z); h.z = __half_as_ushort(t); l.z = __half_as_ushort(__float2half(v.z - __half2float(t)));
    t = __float2half(v.w); h.w = __half_as_ushort(t); l.w = __half_as_ushort(__float2half(v.w - __half2float(t)));
    *reinterpret_cast<ushort4*>(&hi[(size_t)i * 4]) = h;
    *reinterpret_cast<ushort4*>(&lo[(size_t)i * 4]) = l;
}

__global__ void splitT_w_kernel(const float* __restrict__ Wl, const float* __restrict__ Wr, int M,
                                unsigned short* __restrict__ WThi) {
    int k = blockIdx.x;
    int m2 = blockIdx.y * 256 + threadIdx.x;
    if (m2 >= 2 * M) return;
    float v = (m2 < M) ? Wl[(size_t)k * M + m2] : Wr[(size_t)k * M + (m2 - M)];
    WThi[(size_t)m2 * 256 + k] = __half_as_ushort(__float2half(v));
}

// ---------------------------------------------------------------------------
// MFMA GEMM: fp16 2-term split — C = (Ahi + Alo) x B, B plain fp16.
// R7-proven structure: tile 128x128, BK=64, single-buffered LDS (48 KB:
// Ahi, Alo, B), gload_lds staging with pre-swizzled global source.
// Inner loop: 2 MFMA per fragment pair (vs R7's 3), 256 MFMA/wave total.
// Epilogue: cols [0,M) -> fp16 xl buffer; cols [M,2M) -> fp32 xr buffer.
// ---------------------------------------------------------------------------

__global__ __launch_bounds__(256) void gemm_mfma_kernel(
    const unsigned short* __restrict__ Ahi, const unsigned short* __restrict__ Alo,
    const unsigned short* __restrict__ B,
    __half* __restrict__ xl16, float* __restrict__ xr32, int N, int M) {
    __shared__ unsigned short sA[2][128 * 64];
    __shared__ unsigned short sB[128 * 64];

    int t = threadIdx.x;
    int lane = t & 63;
    int w = t >> 6;
    int wr = (w >> 1) * 64;
    int wc = (w & 1) * 64;
    int row0 = blockIdx.x * 128;
    int n0 = blockIdx.y * 128;

    int l15 = lane & 15;
    int l4 = lane >> 4;

    int lr8 = lane >> 3;
    int lc8 = lane & 7;
    int ksw = (lc8 ^ lr8) * 8;

    f32x4 acc[4][4] = {};

    for (int k0 = 0; k0 < 256; k0 += 64) {
        __syncthreads();
        #pragma unroll
        for (int i = 0; i < 4; ++i) {
            int brow = i * 32 + w * 8;
            int row = brow + lr8;
            int ar = row0 + row; if (ar >= N) ar = N - 1;
            int bc = n0 + row;
            gload_lds16(&Ahi[(size_t)ar * 256 + k0 + ksw], &sA[0][brow * 64]);
            gload_lds16(&Alo[(size_t)ar * 256 + k0 + ksw], &sA[1][brow * 64]);
            gload_lds16(&B[(size_t)bc * 256 + k0 + ksw], &sB[brow * 64]);
        }
        __syncthreads();

        #pragma unroll
        for (int ksub = 0; ksub < 2; ++ksub) {
            int kb = ksub * 32 + l4 * 8;
            f16x8 b[4];
            #pragma unroll
            for (int fc = 0; fc < 4; ++fc) {
                int cc = wc + fc * 16 + l15;
                b[fc] = *reinterpret_cast<const f16x8*>(&sB[cc * 64 + (kb ^ ((cc & 7) << 3))]);
            }
            #pragma unroll
            for (int fr = 0; fr < 4; ++fr) {
                int r = wr + fr * 16 + l15;
                int idx = r * 64 + (kb ^ ((r & 7) << 3));
                f16x8 ah = *reinterpret_cast<const f16x8*>(&sA[0][idx]);
                f16x8 al = *reinterpret_cast<const f16x8*>(&sA[1][idx]);
                #pragma unroll
                for (int fc = 0; fc < 4; ++fc) {
                    acc[fr][fc] = __builtin_amdgcn_mfma_f32_16x16x32_f16(ah, b[fc], acc[fr][fc], 0, 0, 0);
                    acc[fr][fc] = __builtin_amdgcn_mfma_f32_16x16x32_f16(al, b[fc], acc[fr][fc], 0, 0, 0);
                }
            }
        }
    }

    #pragma unroll
    for (int fr = 0; fr < 4; ++fr) {
        #pragma unroll
        for (int j = 0; j < 4; ++j) {
            int row = row0 + wr + fr * 16 + l4 * 4 + j;
            if (row < N) {
                #pragma unroll
                for (int fc = 0; fc < 4; ++fc) {
                    int col = n0 + wc + fc * 16 + l15;
                    float v = acc[fr][fc][j];
                    if (col < M) xl16[(size_t)row * M + col] = __float2half(v);
                    else         xr32[(size_t)row * M + (col - M)] = v;
                }
            }
        }
    }
}

// ---------------------------------------------------------------------------
// agg_h8: one wave per node; half = lane>>5 picks edge slot, lane&31 owns
// 8 channels. xl gathered as fp16 (one 16B load/lane/edge); xr read fp32 once.
// Fixed-m softmax (m = self logit), 1-deep pipeline. Output: fp16 hi/lo.
// ---------------------------------------------------------------------------

__global__ __launch_bounds__(256) void agg_h8_kernel(
    const __half* __restrict__ xl16, const float* __restrict__ xr32,
    const float* __restrict__ att, const float* __restrict__ bias,
    const int* __restrict__ row_ptr, const int* __restrict__ csr,
    unsigned short* __restrict__ ohi, unsigned short* __restrict__ olo, int N) {
    int wv = threadIdx.x >> 6;
    int i = blockIdx.x * 4 + wv;
    if (i >= N) return;
    int lane = threadIdx.x & 63;
    int half = lane >> 5;
    int cb = (lane & 31) * 8;

    float rxr[8], a6[8], a4[8];
    {
        float4 r0 = *reinterpret_cast<const float4*>(&xr32[(size_t)i * 256 + cb]);
        float4 r1 = *reinterpret_cast<const float4*>(&xr32[(size_t)i * 256 + cb + 4]);
        rxr[0] = r0.x; rxr[1] = r0.y; rxr[2] = r0.z; rxr[3] = r0.w;
        rxr[4] = r1.x; rxr[5] = r1.y; rxr[6] = r1.z; rxr[7] = r1.w;
        float4 w0 = *reinterpret_cast<const float4*>(&att[cb]);
        float4 w1 = *reinterpret_cast<const float4*>(&att[cb + 4]);
        float aa[8] = {w0.x, w0.y, w0.z, w0.w, w1.x, w1.y, w1.z, w1.w};
        #pragma unroll
        for (int c = 0; c < 8; ++c) { a6[c] = 0.6f * aa[c]; a4[c] = 0.4f * aa[c]; }
    }

    float acc[8], l, m;
    {
        uint4 sv = *reinterpret_cast<const uint4*>(&xl16[(size_t)i * 256 + cb]);
        float u[8];
        h8_to_f(sv, u);
        float p = 0.f;
        #pragma unroll
        for (int c = 0; c < 8; ++c) {
            float v = u[c] + rxr[c];
            p = fmaf(a6[c], v, p);
            p = fmaf(a4[c], fabsf(v), p);
        }
        p += __shfl_xor(p, 1, 4);
        p += __shfl_xor(p, 2, 4);
        m = p;
        l = half ? 0.f : 1.f;
        #pragma unroll
        for (int c = 0; c < 8; ++c) acc[c] = half ? 0.f : u[c];
    }

    int start = row_ptr[i], end = row_ptr[i + 1];

    int kk0 = start + half, kk1 = start + 2 + half;
    int s0 = (kk0 < end) ? csr[kk0] : i;
    int s1 = (kk1 < end) ? csr[kk1] : i;
    uint4 ca = *reinterpret_cast<const uint4*>(&xl16[(size_t)s0 * 256 + cb]);
    uint4 cbv = *reinterpret_cast<const uint4*>(&xl16[(size_t)s1 * 256 + cb]);

    for (int k = start; k < end; k += 4) {
        int nk0 = k + 4 + half, nk1 = k + 6 + half;
        int t0 = (nk0 < end) ? csr[nk0] : i;
        int t1 = (nk1 < end) ? csr[nk1] : i;
        uint4 na = *reinterpret_cast<const uint4*>(&xl16[(size_t)t0 * 256 + cb]);
        uint4 nb = *reinterpret_cast<const uint4*>(&xl16[(size_t)t1 * 256 + cb]);

        float ua[8], ub[8];
        h8_to_f(ca, ua);
        h8_to_f(cbv, ub);
        float p0 = 0.f, p1 = 0.f;
        #pragma unroll
        for (int c = 0; c < 8; ++c) {
            float v0 = ua[c] + rxr[c];
            p0 = fmaf(a6[c], v0, p0);
            p0 = fmaf(a4[c], fabsf(v0), p0);
            float v1 = ub[c] + rxr[c];
            p1 = fmaf(a6[c], v1, p1);
            p1 = fmaf(a4[c], fabsf(v1), p1);
        }
        p0 += __shfl_xor(p0, 1, 4);
        p0 += __shfl_xor(p0, 2, 4);
        p1 += __shfl_xor(p1, 1, 4);
        p1 += __shfl_xor(p1, 2, 4);
        float e0 = (k + half < end)     ? __expf(fminf(p0 - m, 60.f)) : 0.f;
        float e1 = (k + 2 + half < end) ? __expf(fminf(p1 - m, 60.f)) : 0.f;
        l += e0 + e1;
        #pragma unroll
        for (int c = 0; c < 8; ++c) acc[c] = fmaf(e0, ua[c], fmaf(e1, ub[c], acc[c]));

        ca = na; cbv = nb;
    }

    l += __shfl_xor(l, 32, 64);
    #pragma unroll
    for (int c = 0; c < 8; ++c) acc[c] += __shfl_xor(acc[c], 32, 64);

    if (half == 0) {
        float4 bb0 = *reinterpret_cast<const float4*>(&bias[cb]);
        float4 bb1 = *reinterpret_cast<const float4*>(&bias[cb + 4]);
        float bs[8] = {bb0.x, bb0.y, bb0.z, bb0.w, bb1.x, bb1.y, bb1.z, bb1.w};
        float inv = 1.0f / l;
        unsigned int hw[4], lw[4];
        #pragma unroll
        for (int c2 = 0; c2 < 4; ++c2) {
            float r0 = fmaf(acc[2 * c2], inv, bs[2 * c2]);
            float r1 = fmaf(acc[2 * c2 + 1], inv, bs[2 * c2 + 1]);
            r0 = (r0 > 0.f) ? r0 : (__expf(r0) - 1.f);
            r1 = (r1 > 0.f) ? r1 : (__expf(r1) - 1.f);
            __half th0 = __float2half(r0);
            __half th1 = __float2half(r1);
            unsigned short h0 = __half_as_ushort(th0), h1 = __half_as_ushort(th1);
            float f0 = r0 - __half2float(th0);
            float f1 = r1 - __half2float(th1);
            unsigned short l0 = __half_as_ushort(__float2half(f0));
            unsigned short l1 = __half_as_ushort(__float2half(f1));
            hw[c2] = (unsigned int)h0 | ((unsigned int)h1 << 16);
            lw[c2] = (unsigned int)l0 | ((unsigned int)l1 << 16);
        }
        *reinterpret_cast<uint4*>(&ohi[(size_t)i * 256 + cb]) = make_uint4(hw[0], hw[1], hw[2], hw[3]);
        *reinterpret_cast<uint4*>(&olo[(size_t)i * 256 + cb]) = make_uint4(lw[0], lw[1], lw[2], lw[3]);
    }
}

// ---------------------------------------------------------------------------
// agg_h1 (layer 3): one wave per node, 8 edge slots x 8 lanes x 8 ch.
// xl gathered as fp16. Fixed-m softmax, 1-deep pipeline.
// ---------------------------------------------------------------------------

__global__ __launch_bounds__(256) void agg_h1_kernel(
    const __half* __restrict__ xl16, const float* __restrict__ xr32,
    const float* __restrict__ att, const float* __restrict__ bias,
    const int* __restrict__ row_ptr, const int* __restrict__ csr,
    float* __restrict__ out, int N) {
    int wv = threadIdx.x >> 6;
    int i = blockIdx.x * 4 + wv;
    if (i >= N) return;
    int lane = threadIdx.x & 63;
    int es = lane >> 3;
    int cb = (lane & 7) * 8;

    float rxr[8], a6[8], a4[8];
    {
        float4 r0 = *reinterpret_cast<const float4*>(&xr32[(size_t)i * 64 + cb]);
        float4 r1 = *reinterpret_cast<const float4*>(&xr32[(size_t)i * 64 + cb + 4]);
        rxr[0] = r0.x; rxr[1] = r0.y; rxr[2] = r0.z; rxr[3] = r0.w;
        rxr[4] = r1.x; rxr[5] = r1.y; rxr[6] = r1.z; rxr[7] = r1.w;
        float4 w0 = *reinterpret_cast<const float4*>(&att[cb]);
        float4 w1 = *reinterpret_cast<const float4*>(&att[cb + 4]);
        float aa[8] = {w0.x, w0.y, w0.z, w0.w, w1.x, w1.y, w1.z, w1.w};
        #pragma unroll
        for (int c = 0; c < 8; ++c) { a6[c] = 0.6f * aa[c]; a4[c] = 0.4f * aa[c]; }
    }

    float acc[8], l, m;
    {
        uint4 sv = *reinterpret_cast<const uint4*>(&xl16[(size_t)i * 64 + cb]);
        float u[8];
        h8_to_f(sv, u);
        float p = 0.f;
        #pragma unroll
        for (int c = 0; c < 8; ++c) {
            float v = u[c] + rxr[c];
            p = fmaf(a6[c], v, p);
            p = fmaf(a4[c], fabsf(v), p);
        }
        p += __shfl_xor(p, 1, 8);
        p += __shfl_xor(p, 2, 8);
        p += __shfl_xor(p, 4, 8);
        m = p;
        l = es ? 0.f : 1.f;
        #pragma unroll
        for (int c = 0; c < 8; ++c) acc[c] = es ? 0.f : u[c];
    }

    int start = row_ptr[i], end = row_ptr[i + 1];

    int kk = start + es;
    int s = (kk < end) ? csr[kk] : i;
    uint4 cu = *reinterpret_cast<const uint4*>(&xl16[(size_t)s * 64 + cb]);

    for (int k = start; k < end; k += 8) {
        int nk = k + 8 + es;
        int tn = (nk < end) ? csr[nk] : i;
        uint4 nu = *reinterpret_cast<const uint4*>(&xl16[(size_t)tn * 64 + cb]);

        float u[8];
        h8_to_f(cu, u);
        float p = 0.f;
        #pragma unroll
        for (int c = 0; c < 8; ++c) {
            float v = u[c] + rxr[c];
            p = fmaf(a6[c], v, p);
            p = fmaf(a4[c], fabsf(v), p);
        }
        p += __shfl_xor(p, 1, 8);
        p += __shfl_xor(p, 2, 8);
        p += __shfl_xor(p, 4, 8);
        float e = (k + es < end) ? __expf(fminf(p - m, 60.f)) : 0.f;
        l += e;
        #pragma unroll
        for (int c = 0; c < 8; ++c) acc[c] = fmaf(e, u[c], acc[c]);

        cu = nu;
    }

    l += __shfl_xor(l, 8, 64);
    l += __shfl_xor(l, 16, 64);
    l += __shfl_xor(l, 32, 64);
    #pragma unroll
    for (int c = 0; c < 8; ++c) {
        acc[c] += __shfl_xor(acc[c], 8, 64);
        acc[c] += __shfl_xor(acc[c], 16, 64);
        acc[c] += __shfl_xor(acc[c], 32, 64);
    }

    if (es == 0) {
        float inv = 1.0f / l;
        float4 bb0 = *reinterpret_cast<const float4*>(&bias[cb]);
        float4 bb1 = *reinterpret_cast<const float4*>(&bias[cb + 4]);
        float4 o0, o1;
        o0.x = fmaf(acc[0], inv, bb0.x);
        o0.y = fmaf(acc[1], inv, bb0.y);
        o0.z = fmaf(acc[2], inv, bb0.z);
        o0.w = fmaf(acc[3], inv, bb0.w);
        o1.x = fmaf(acc[4], inv, bb1.x);
        o1.y = fmaf(acc[5], inv, bb1.y);
        o1.z = fmaf(acc[6], inv, bb1.z);
        o1.w = fmaf(acc[7], inv, bb1.w);
        *reinterpret_cast<float4*>(&out[(size_t)i * 64 + cb]) = o0;
        *reinterpret_cast<float4*>(&out[(size_t)i * 64 + cb + 4]) = o1;
    }
}

// ---------------------------------------------------------------------------

extern "C" void kernel_launch(void* const* d_in, const int* in_sizes, int n_in,
                              void* d_out, int out_size, void* d_ws, size_t ws_size,
                              hipStream_t stream) {
    const float* x    = (const float*)d_in[0];
    const void*  ei   = d_in[1];
    const float* Wl1  = (const float*)d_in[2];
    const float* Wr1  = (const float*)d_in[3];
    const float* att1 = (const float*)d_in[4];
    const float* b1   = (const float*)d_in[5];
    const float* Wl2  = (const float*)d_in[6];
    const float* Wr2  = (const float*)d_in[7];
    const float* att2 = (const float*)d_in[8];
    const float* b2   = (const float*)d_in[9];
    const float* Wl3  = (const float*)d_in[10];
    const float* Wr3  = (const float*)d_in[11];
    const float* att3 = (const float*)d_in[12];
    const float* b3   = (const float*)d_in[13];
    float* out = (float*)d_out;

    int N = in_sizes[0] / 256;
    int E = in_sizes[1] / 2;

    char* w = (char*)d_ws;
    unsigned short* h_hi = (unsigned short*)w; w += (size_t)N * 256 * 2;
    unsigned short* h_lo = (unsigned short*)w; w += (size_t)N * 256 * 2;
    __half* xl16 = (__half*)w;     w += (size_t)N * 256 * 2;
    float* xr32 = (float*)w;       w += (size_t)N * 256 * sizeof(float);
    unsigned short* WT_hi = (unsigned short*)w; w += (size_t)512 * 256 * 2;
    int* row_ptr = (int*)w; w += ((size_t)N + 2) * sizeof(int);
    int* deg     = (int*)w; w += (size_t)N * sizeof(int);
    int* csr     = (int*)w; w += (size_t)E * sizeof(int);
    int* flag    = (int*)w; w += 256;
    int* partial = (int*)w; w += 256;

    // --- CSR build ---
    detect_i64_kernel<<<1, 256, 0, stream>>>((const unsigned int*)ei, E, flag);
    hipMemsetAsync(deg, 0, (size_t)N * sizeof(int), stream);
    count_deg_kernel<<<(E + 255) / 256, 256, 0, stream>>>(ei, E, flag, deg);
    int nb = (N + 1023) / 1024;
    scan_block_kernel<<<nb, 1024, 0, stream>>>(deg, row_ptr, partial, N);
    scan_top_kernel<<<1, 64, 0, stream>>>(partial, nb);
    scan_addoff_kernel<<<(N + 255) / 256, 256, 0, stream>>>(row_ptr, partial, N);
    hipMemsetAsync(deg, 0, (size_t)N * sizeof(int), stream);
    scatter_kernel<<<(E + 255) / 256, 256, 0, stream>>>(ei, E, flag, row_ptr, deg, csr);

    int gemm_gx = (N + 127) / 128;
    int agg_g = (N + 3) / 4;

    // --- Layer 1 ---
    split_kernel<<<((N * 256 / 4) + 255) / 256, 256, 0, stream>>>(x, N * 256 / 4, h_hi, h_lo);
    splitT_w_kernel<<<dim3(256, 2), 256, 0, stream>>>(Wl1, Wr1, 256, WT_hi);
    gemm_mfma_kernel<<<dim3(gemm_gx, 4), 256, 0, stream>>>(h_hi, h_lo, WT_hi, xl16, xr32, N, 256);
    agg_h8_kernel<<<agg_g, 256, 0, stream>>>(xl16, xr32, att1, b1, row_ptr, csr, h_hi, h_lo, N);

    // --- Layer 2 ---
    splitT_w_kernel<<<dim3(256, 2), 256, 0, stream>>>(Wl2, Wr2, 256, WT_hi);
    gemm_mfma_kernel<<<dim3(gemm_gx, 4), 256, 0, stream>>>(h_hi, h_lo, WT_hi, xl16, xr32, N, 256);
    agg_h8_kernel<<<agg_g, 256, 0, stream>>>(xl16, xr32, att2, b2, row_ptr, csr, h_hi, h_lo, N);

    // --- Layer 3 ---
    splitT_w_kernel<<<dim3(256, 1), 256, 0, stream>>>(Wl3, Wr3, 64, WT_hi);
    gemm_mfma_kernel<<<dim3(gemm_gx, 1), 256, 0, stream>>>(h_hi, h_lo, WT_hi, xl16, xr32, N, 64);
    agg_h1_kernel<<<agg_g, 256, 0, stream>>>(xl16, xr32, att3, b3, row_ptr, csr, out, N);
}

// Round 12
// 381.943 us; speedup vs baseline: 1.4296x; 1.0817x over previous
//
#include <hip/hip_runtime.h>
#include <hip/hip_fp16.h>

#define NEG_SLOPE 0.2f

typedef __attribute__((ext_vector_type(8))) _Float16 f16x8;
typedef __attribute__((ext_vector_type(2))) _Float16 f16x2;
typedef __attribute__((ext_vector_type(4))) float f32x4;

__device__ __forceinline__ void gload_lds16(const unsigned short* g, unsigned short* lds) {
    __builtin_amdgcn_global_load_lds(
        (const __attribute__((address_space(1))) void*)g,
        (__attribute__((address_space(3))) void*)lds, 16, 0, 0);
}

__device__ __forceinline__ f16x2 habs2(f16x2 v) {
    unsigned int u = __builtin_bit_cast(unsigned int, v) & 0x7FFF7FFFu;
    return __builtin_bit_cast(f16x2, u);
}

// ---------------------------------------------------------------------------
// CSR build
// ---------------------------------------------------------------------------

__global__ void detect_i64_kernel(const unsigned int* __restrict__ w, int E, int* __restrict__ flag) {
    __shared__ unsigned int ssum[256];
    int n = E < 4096 ? E : 4096;
    unsigned int local = 0;
    for (int k = threadIdx.x; k < n; k += 256) local |= w[2 * k + 1];
    ssum[threadIdx.x] = local;
    __syncthreads();
    for (int off = 128; off > 0; off >>= 1) {
        if (threadIdx.x < off) ssum[threadIdx.x] |= ssum[threadIdx.x + off];
        __syncthreads();
    }
    if (threadIdx.x == 0) flag[0] = (ssum[0] == 0) ? 1 : 0;
}

__global__ void count_deg_kernel(const void* __restrict__ eiv, int E,
                                 const int* __restrict__ flag, int* __restrict__ deg) {
    int e = blockIdx.x * blockDim.x + threadIdx.x;
    if (e >= E) return;
    int d;
    if (*flag) d = (int)((const long long*)eiv)[(size_t)E + e];
    else       d = ((const int*)eiv)[(size_t)E + e];
    atomicAdd(&deg[d], 1);
}

__global__ void scan_block_kernel(const int* __restrict__ deg, int* __restrict__ row_ptr,
                                  int* __restrict__ partial, int N) {
    __shared__ int sd[1024];
    int t = threadIdx.x;
    int g = blockIdx.x * 1024 + t;
    int v = (g < N) ? deg[g] : 0;
    sd[t] = v;
    __syncthreads();
    for (int off = 1; off < 1024; off <<= 1) {
        int add = (t >= off) ? sd[t - off] : 0;
        __syncthreads();
        sd[t] += add;
        __syncthreads();
    }
    if (g < N) row_ptr[g + 1] = sd[t];
    if (t == 1023) partial[blockIdx.x] = sd[1023];
    if (g == 0) row_ptr[0] = 0;
}

__global__ void scan_top_kernel(int* __restrict__ partial, int nb) {
    if (threadIdx.x == 0 && blockIdx.x == 0) {
        int run = 0;
        for (int j = 0; j < nb; ++j) { run += partial[j]; partial[j] = run; }
    }
}

__global__ void scan_addoff_kernel(int* __restrict__ row_ptr, const int* __restrict__ partial, int N) {
    int g = blockIdx.x * 256 + threadIdx.x;
    if (g >= N) return;
    int b = g >> 10;
    if (b > 0) row_ptr[g + 1] += partial[b - 1];
}

__global__ void scatter_kernel(const void* __restrict__ eiv, int E,
                               const int* __restrict__ flag,
                               const int* __restrict__ row_ptr,
                               int* __restrict__ cursor, int* __restrict__ csr) {
    int e = blockIdx.x * blockDim.x + threadIdx.x;
    if (e >= E) return;
    int s, d;
    if (*flag) {
        s = (int)((const long long*)eiv)[e];
        d = (int)((const long long*)eiv)[(size_t)E + e];
    } else {
        s = ((const int*)eiv)[e];
        d = ((const int*)eiv)[(size_t)E + e];
    }
    int pos = atomicAdd(&cursor[d], 1);
    csr[row_ptr[d] + pos] = s;
}

// ---------------------------------------------------------------------------
// fp32 -> fp16 convert (A operand, layer 1); weights -> fp16 transposed
// ---------------------------------------------------------------------------

__global__ void to_f16_kernel(const float* __restrict__ src, int n4,
                              unsigned short* __restrict__ dst) {
    int i = blockIdx.x * blockDim.x + threadIdx.x;
    if (i >= n4) return;
    float4 v = *reinterpret_cast<const float4*>(&src[(size_t)i * 4]);
    ushort4 h;
    h.x = __half_as_ushort(__float2half(v.x));
    h.y = __half_as_ushort(__float2half(v.y));
    h.z = __half_as_ushort(__float2half(v.z));
    h.w = __half_as_ushort(__float2half(v.w));
    *reinterpret_cast<ushort4*>(&dst[(size_t)i * 4]) = h;
}

__global__ void splitT_w_kernel(const float* __restrict__ Wl, const float* __restrict__ Wr, int M,
                                unsigned short* __restrict__ WT) {
    int k = blockIdx.x;
    int m2 = blockIdx.y * 256 + threadIdx.x;
    if (m2 >= 2 * M) return;
    float v = (m2 < M) ? Wl[(size_t)k * M + m2] : Wr[(size_t)k * M + (m2 - M)];
    WT[(size_t)m2 * 256 + k] = __half_as_ushort(__float2half(v));
}

// ---------------------------------------------------------------------------
// MFMA GEMM: plain fp16 single-pass. Tile 128x128, BK=64, single-buffered LDS
// (32 KB: A, B), gload_lds staging with pre-swizzled global source (R7/R11
// proven). 128 MFMA/wave. Epilogue: cols [0,M) -> fp16 xl; [M,2M) -> fp32 xr.
// ---------------------------------------------------------------------------

__global__ __launch_bounds__(256) void gemm_mfma_kernel(
    const unsigned short* __restrict__ A, const unsigned short* __restrict__ B,
    __half* __restrict__ xl16, float* __restrict__ xr32, int N, int M) {
    __shared__ unsigned short sA[128 * 64];
    __shared__ unsigned short sB[128 * 64];

    int t = threadIdx.x;
    int lane = t & 63;
    int w = t >> 6;
    int wr = (w >> 1) * 64;
    int wc = (w & 1) * 64;
    int row0 = blockIdx.x * 128;
    int n0 = blockIdx.y * 128;

    int l15 = lane & 15;
    int l4 = lane >> 4;

    int lr8 = lane >> 3;
    int lc8 = lane & 7;
    int ksw = (lc8 ^ lr8) * 8;

    f32x4 acc[4][4] = {};

    for (int k0 = 0; k0 < 256; k0 += 64) {
        __syncthreads();
        #pragma unroll
        for (int i = 0; i < 4; ++i) {
            int brow = i * 32 + w * 8;
            int row = brow + lr8;
            int ar = row0 + row; if (ar >= N) ar = N - 1;
            int bc = n0 + row;
            gload_lds16(&A[(size_t)ar * 256 + k0 + ksw], &sA[brow * 64]);
            gload_lds16(&B[(size_t)bc * 256 + k0 + ksw], &sB[brow * 64]);
        }
        __syncthreads();

        #pragma unroll
        for (int ksub = 0; ksub < 2; ++ksub) {
            int kb = ksub * 32 + l4 * 8;
            f16x8 b[4];
            #pragma unroll
            for (int fc = 0; fc < 4; ++fc) {
                int cc = wc + fc * 16 + l15;
                b[fc] = *reinterpret_cast<const f16x8*>(&sB[cc * 64 + (kb ^ ((cc & 7) << 3))]);
            }
            #pragma unroll
            for (int fr = 0; fr < 4; ++fr) {
                int r = wr + fr * 16 + l15;
                f16x8 a = *reinterpret_cast<const f16x8*>(&sA[r * 64 + (kb ^ ((r & 7) << 3))]);
                #pragma unroll
                for (int fc = 0; fc < 4; ++fc) {
                    acc[fr][fc] = __builtin_amdgcn_mfma_f32_16x16x32_f16(a, b[fc], acc[fr][fc], 0, 0, 0);
                }
            }
        }
    }

    #pragma unroll
    for (int fr = 0; fr < 4; ++fr) {
        #pragma unroll
        for (int j = 0; j < 4; ++j) {
            int row = row0 + wr + fr * 16 + l4 * 4 + j;
            if (row < N) {
                #pragma unroll
                for (int fc = 0; fc < 4; ++fc) {
                    int col = n0 + wc + fc * 16 + l15;
                    float v = acc[fr][fc][j];
                    if (col < M) xl16[(size_t)row * M + col] = __float2half(v);
                    else         xr32[(size_t)row * M + (col - M)] = v;
                }
            }
        }
    }
}

// ---------------------------------------------------------------------------
// agg_h8: one wave per node; half = lane>>5 picks edge slot, lane&31 owns
// 8 channels. xl gathered as fp16; logit computed in PACKED fp16 (pk_add +
// packed abs + v_dot2_f32_f16 — exact f16xf16->f32 accumulate). xr read fp32,
// packed to fp16 once per node. Fixed-m softmax, 1-deep pipeline. f32 acc.
// Output: fp16 (feeds next layer's fp16 GEMM A).
// ---------------------------------------------------------------------------

__global__ __launch_bounds__(256) void agg_h8_kernel(
    const __half* __restrict__ xl16, const float* __restrict__ xr32,
    const float* __restrict__ att, const float* __restrict__ bias,
    const int* __restrict__ row_ptr, const int* __restrict__ csr,
    unsigned short* __restrict__ oh, int N) {
    int wv = threadIdx.x >> 6;
    int i = blockIdx.x * 4 + wv;
    if (i >= N) return;
    int lane = threadIdx.x & 63;
    int half = lane >> 5;
    int cb = (lane & 31) * 8;

    f16x2 r2[4], a62[4], a42[4];
    float rxr[8];
    {
        float4 r0 = *reinterpret_cast<const float4*>(&xr32[(size_t)i * 256 + cb]);
        float4 r1 = *reinterpret_cast<const float4*>(&xr32[(size_t)i * 256 + cb + 4]);
        rxr[0] = r0.x; rxr[1] = r0.y; rxr[2] = r0.z; rxr[3] = r0.w;
        rxr[4] = r1.x; rxr[5] = r1.y; rxr[6] = r1.z; rxr[7] = r1.w;
        float4 w0 = *reinterpret_cast<const float4*>(&att[cb]);
        float4 w1 = *reinterpret_cast<const float4*>(&att[cb + 4]);
        float aa[8] = {w0.x, w0.y, w0.z, w0.w, w1.x, w1.y, w1.z, w1.w};
        #pragma unroll
        for (int j = 0; j < 4; ++j) {
            r2[j]  = f16x2{(_Float16)rxr[2 * j], (_Float16)rxr[2 * j + 1]};
            a62[j] = f16x2{(_Float16)(0.6f * aa[2 * j]), (_Float16)(0.6f * aa[2 * j + 1])};
            a42[j] = f16x2{(_Float16)(0.4f * aa[2 * j]), (_Float16)(0.4f * aa[2 * j + 1])};
        }
    }

    float acc[8], l, m;
    {
        uint4 sv = *reinterpret_cast<const uint4*>(&xl16[(size_t)i * 256 + cb]);
        const f16x2* u2 = reinterpret_cast<const f16x2*>(&sv);
        float p = 0.f;
        #pragma unroll
        for (int j = 0; j < 4; ++j) {
            f16x2 v2 = u2[j] + r2[j];
            p = __builtin_amdgcn_fdot2(a62[j], v2, p, false);
            p = __builtin_amdgcn_fdot2(a42[j], habs2(v2), p, false);
        }
        p += __shfl_xor(p, 1, 4);
        p += __shfl_xor(p, 2, 4);
        m = p;
        l = half ? 0.f : 1.f;
        #pragma unroll
        for (int j = 0; j < 4; ++j) {
            acc[2 * j]     = half ? 0.f : (float)u2[j][0];
            acc[2 * j + 1] = half ? 0.f : (float)u2[j][1];
        }
    }

    int start = row_ptr[i], end = row_ptr[i + 1];

    int kk0 = start + half, kk1 = start + 2 + half;
    int s0 = (kk0 < end) ? csr[kk0] : i;
    int s1 = (kk1 < end) ? csr[kk1] : i;
    uint4 ca = *reinterpret_cast<const uint4*>(&xl16[(size_t)s0 * 256 + cb]);
    uint4 cbv = *reinterpret_cast<const uint4*>(&xl16[(size_t)s1 * 256 + cb]);

    for (int k = start; k < end; k += 4) {
        int nk0 = k + 4 + half, nk1 = k + 6 + half;
        int t0 = (nk0 < end) ? csr[nk0] : i;
        int t1 = (nk1 < end) ? csr[nk1] : i;
        uint4 na = *reinterpret_cast<const uint4*>(&xl16[(size_t)t0 * 256 + cb]);
        uint4 nb = *reinterpret_cast<const uint4*>(&xl16[(size_t)t1 * 256 + cb]);

        const f16x2* ua2 = reinterpret_cast<const f16x2*>(&ca);
        const f16x2* ub2 = reinterpret_cast<const f16x2*>(&cbv);
        float p0 = 0.f, p1 = 0.f;
        #pragma unroll
        for (int j = 0; j < 4; ++j) {
            f16x2 v0 = ua2[j] + r2[j];
            p0 = __builtin_amdgcn_fdot2(a62[j], v0, p0, false);
            p0 = __builtin_amdgcn_fdot2(a42[j], habs2(v0), p0, false);
            f16x2 v1 = ub2[j] + r2[j];
            p1 = __builtin_amdgcn_fdot2(a62[j], v1, p1, false);
            p1 = __builtin_amdgcn_fdot2(a42[j], habs2(v1), p1, false);
        }
        p0 += __shfl_xor(p0, 1, 4);
        p0 += __shfl_xor(p0, 2, 4);
        p1 += __shfl_xor(p1, 1, 4);
        p1 += __shfl_xor(p1, 2, 4);
        float e0 = (k + half < end)     ? __expf(fminf(p0 - m, 60.f)) : 0.f;
        float e1 = (k + 2 + half < end) ? __expf(fminf(p1 - m, 60.f)) : 0.f;
        l += e0 + e1;
        #pragma unroll
        for (int j = 0; j < 4; ++j) {
            acc[2 * j]     = fmaf(e0, (float)ua2[j][0], fmaf(e1, (float)ub2[j][0], acc[2 * j]));
            acc[2 * j + 1] = fmaf(e0, (float)ua2[j][1], fmaf(e1, (float)ub2[j][1], acc[2 * j + 1]));
        }

        ca = na; cbv = nb;
    }

    l += __shfl_xor(l, 32, 64);
    #pragma unroll
    for (int c = 0; c < 8; ++c) acc[c] += __shfl_xor(acc[c], 32, 64);

    if (half == 0) {
        float4 bb0 = *reinterpret_cast<const float4*>(&bias[cb]);
        float4 bb1 = *reinterpret_cast<const float4*>(&bias[cb + 4]);
        float bs[8] = {bb0.x, bb0.y, bb0.z, bb0.w, bb1.x, bb1.y, bb1.z, bb1.w};
        float inv = 1.0f / l;
        unsigned int hw[4];
        #pragma unroll
        for (int c2 = 0; c2 < 4; ++c2) {
            float r0 = fmaf(acc[2 * c2], inv, bs[2 * c2]);
            float r1 = fmaf(acc[2 * c2 + 1], inv, bs[2 * c2 + 1]);
            r0 = (r0 > 0.f) ? r0 : (__expf(r0) - 1.f);
            r1 = (r1 > 0.f) ? r1 : (__expf(r1) - 1.f);
            unsigned short h0 = __half_as_ushort(__float2half(r0));
            unsigned short h1 = __half_as_ushort(__float2half(r1));
            hw[c2] = (unsigned int)h0 | ((unsigned int)h1 << 16);
        }
        *reinterpret_cast<uint4*>(&oh[(size_t)i * 256 + cb]) = make_uint4(hw[0], hw[1], hw[2], hw[3]);
    }
}

// ---------------------------------------------------------------------------
// agg_h1 (layer 3): one wave per node, 8 edge slots x 8 lanes x 8 ch.
// Packed-fp16 logit, f32 accumulation, fixed-m softmax, 1-deep pipeline.
// ---------------------------------------------------------------------------

__global__ __launch_bounds__(256) void agg_h1_kernel(
    const __half* __restrict__ xl16, const float* __restrict__ xr32,
    const float* __restrict__ att, const float* __restrict__ bias,
    const int* __restrict__ row_ptr, const int* __restrict__ csr,
    float* __restrict__ out, int N) {
    int wv = threadIdx.x >> 6;
    int i = blockIdx.x * 4 + wv;
    if (i >= N) return;
    int lane = threadIdx.x & 63;
    int es = lane >> 3;
    int cb = (lane & 7) * 8;

    f16x2 r2[4], a62[4], a42[4];
    {
        float4 r0 = *reinterpret_cast<const float4*>(&xr32[(size_t)i * 64 + cb]);
        float4 r1 = *reinterpret_cast<const float4*>(&xr32[(size_t)i * 64 + cb + 4]);
        float rr[8] = {r0.x, r0.y, r0.z, r0.w, r1.x, r1.y, r1.z, r1.w};
        float4 w0 = *reinterpret_cast<const float4*>(&att[cb]);
        float4 w1 = *reinterpret_cast<const float4*>(&att[cb + 4]);
        float aa[8] = {w0.x, w0.y, w0.z, w0.w, w1.x, w1.y, w1.z, w1.w};
        #pragma unroll
        for (int j = 0; j < 4; ++j) {
            r2[j]  = f16x2{(_Float16)rr[2 * j], (_Float16)rr[2 * j + 1]};
            a62[j] = f16x2{(_Float16)(0.6f * aa[2 * j]), (_Float16)(0.6f * aa[2 * j + 1])};
            a42[j] = f16x2{(_Float16)(0.4f * aa[2 * j]), (_Float16)(0.4f * aa[2 * j + 1])};
        }
    }

    float acc[8], l, m;
    {
        uint4 sv = *reinterpret_cast<const uint4*>(&xl16[(size_t)i * 64 + cb]);
        const f16x2* u2 = reinterpret_cast<const f16x2*>(&sv);
        float p = 0.f;
        #pragma unroll
        for (int j = 0; j < 4; ++j) {
            f16x2 v2 = u2[j] + r2[j];
            p = __builtin_amdgcn_fdot2(a62[j], v2, p, false);
            p = __builtin_amdgcn_fdot2(a42[j], habs2(v2), p, false);
        }
        p += __shfl_xor(p, 1, 8);
        p += __shfl_xor(p, 2, 8);
        p += __shfl_xor(p, 4, 8);
        m = p;
        l = es ? 0.f : 1.f;
        #pragma unroll
        for (int j = 0; j < 4; ++j) {
            acc[2 * j]     = es ? 0.f : (float)u2[j][0];
            acc[2 * j + 1] = es ? 0.f : (float)u2[j][1];
        }
    }

    int start = row_ptr[i], end = row_ptr[i + 1];

    int kk = start + es;
    int s = (kk < end) ? csr[kk] : i;
    uint4 cu = *reinterpret_cast<const uint4*>(&xl16[(size_t)s * 64 + cb]);

    for (int k = start; k < end; k += 8) {
        int nk = k + 8 + es;
        int tn = (nk < end) ? csr[nk] : i;
        uint4 nu = *reinterpret_cast<const uint4*>(&xl16[(size_t)tn * 64 + cb]);

        const f16x2* u2 = reinterpret_cast<const f16x2*>(&cu);
        float p = 0.f;
        #pragma unroll
        for (int j = 0; j < 4; ++j) {
            f16x2 v2 = u2[j] + r2[j];
            p = __builtin_amdgcn_fdot2(a62[j], v2, p, false);
            p = __builtin_amdgcn_fdot2(a42[j], habs2(v2), p, false);
        }
        p += __shfl_xor(p, 1, 8);
        p += __shfl_xor(p, 2, 8);
        p += __shfl_xor(p, 4, 8);
        float e = (k + es < end) ? __expf(fminf(p - m, 60.f)) : 0.f;
        l += e;
        #pragma unroll
        for (int j = 0; j < 4; ++j) {
            acc[2 * j]     = fmaf(e, (float)u2[j][0], acc[2 * j]);
            acc[2 * j + 1] = fmaf(e, (float)u2[j][1], acc[2 * j + 1]);
        }

        cu = nu;
    }

    l += __shfl_xor(l, 8, 64);
    l += __shfl_xor(l, 16, 64);
    l += __shfl_xor(l, 32, 64);
    #pragma unroll
    for (int c = 0; c < 8; ++c) {
        acc[c] += __shfl_xor(acc[c], 8, 64);
        acc[c] += __shfl_xor(acc[c], 16, 64);
        acc[c] += __shfl_xor(acc[c], 32, 64);
    }

    if (es == 0) {
        float inv = 1.0f / l;
        float4 bb0 = *reinterpret_cast<const float4*>(&bias[cb]);
        float4 bb1 = *reinterpret_cast<const float4*>(&bias[cb + 4]);
        float4 o0, o1;
        o0.x = fmaf(acc[0], inv, bb0.x);
        o0.y = fmaf(acc[1], inv, bb0.y);
        o0.z = fmaf(acc[2], inv, bb0.z);
        o0.w = fmaf(acc[3], inv, bb0.w);
        o1.x = fmaf(acc[4], inv, bb1.x);
        o1.y = fmaf(acc[5], inv, bb1.y);
        o1.z = fmaf(acc[6], inv, bb1.z);
        o1.w = fmaf(acc[7], inv, bb1.w);
        *reinterpret_cast<float4*>(&out[(size_t)i * 64 + cb]) = o0;
        *reinterpret_cast<float4*>(&out[(size_t)i * 64 + cb + 4]) = o1;
    }
}

// ---------------------------------------------------------------------------

extern "C" void kernel_launch(void* const* d_in, const int* in_sizes, int n_in,
                              void* d_out, int out_size, void* d_ws, size_t ws_size,
                              hipStream_t stream) {
    const float* x    = (const float*)d_in[0];
    const void*  ei   = d_in[1];
    const float* Wl1  = (const float*)d_in[2];
    const float* Wr1  = (const float*)d_in[3];
    const float* att1 = (const float*)d_in[4];
    const float* b1   = (const float*)d_in[5];
    const float* Wl2  = (const float*)d_in[6];
    const float* Wr2  = (const float*)d_in[7];
    const float* att2 = (const float*)d_in[8];
    const float* b2   = (const float*)d_in[9];
    const float* Wl3  = (const float*)d_in[10];
    const float* Wr3  = (const float*)d_in[11];
    const float* att3 = (const float*)d_in[12];
    const float* b3   = (const float*)d_in[13];
    float* out = (float*)d_out;

    int N = in_sizes[0] / 256;
    int E = in_sizes[1] / 2;

    char* w = (char*)d_ws;
    unsigned short* a16  = (unsigned short*)w; w += (size_t)N * 256 * 2;  // GEMM A operand
    __half* xl16 = (__half*)w;     w += (size_t)N * 256 * 2;
    float* xr32 = (float*)w;       w += (size_t)N * 256 * sizeof(float);
    unsigned short* WT = (unsigned short*)w; w += (size_t)512 * 256 * 2;
    int* row_ptr = (int*)w; w += ((size_t)N + 2) * sizeof(int);
    int* deg     = (int*)w; w += (size_t)N * sizeof(int);
    int* csr     = (int*)w; w += (size_t)E * sizeof(int);
    int* flag    = (int*)w; w += 256;
    int* partial = (int*)w; w += 256;

    // --- CSR build ---
    detect_i64_kernel<<<1, 256, 0, stream>>>((const unsigned int*)ei, E, flag);
    hipMemsetAsync(deg, 0, (size_t)N * sizeof(int), stream);
    count_deg_kernel<<<(E + 255) / 256, 256, 0, stream>>>(ei, E, flag, deg);
    int nb = (N + 1023) / 1024;
    scan_block_kernel<<<nb, 1024, 0, stream>>>(deg, row_ptr, partial, N);
    scan_top_kernel<<<1, 64, 0, stream>>>(partial, nb);
    scan_addoff_kernel<<<(N + 255) / 256, 256, 0, stream>>>(row_ptr, partial, N);
    hipMemsetAsync(deg, 0, (size_t)N * sizeof(int), stream);
    scatter_kernel<<<(E + 255) / 256, 256, 0, stream>>>(ei, E, flag, row_ptr, deg, csr);

    int gemm_gx = (N + 127) / 128;
    int agg_g = (N + 3) / 4;

    // --- Layer 1 ---
    to_f16_kernel<<<((N * 256 / 4) + 255) / 256, 256, 0, stream>>>(x, N * 256 / 4, a16);
    splitT_w_kernel<<<dim3(256, 2), 256, 0, stream>>>(Wl1, Wr1, 256, WT);
    gemm_mfma_kernel<<<dim3(gemm_gx, 4), 256, 0, stream>>>(a16, WT, xl16, xr32, N, 256);
    agg_h8_kernel<<<agg_g, 256, 0, stream>>>(xl16, xr32, att1, b1, row_ptr, csr, a16, N);

    // --- Layer 2 ---
    splitT_w_kernel<<<dim3(256, 2), 256, 0, stream>>>(Wl2, Wr2, 256, WT);
    gemm_mfma_kernel<<<dim3(gemm_gx, 4), 256, 0, stream>>>(a16, WT, xl16, xr32, N, 256);
    agg_h8_kernel<<<agg_g, 256, 0, stream>>>(xl16, xr32, att2, b2, row_ptr, csr, a16, N);

    // --- Layer 3 ---
    splitT_w_kernel<<<dim3(256, 1), 256, 0, stream>>>(Wl3, Wr3, 64, WT);
    gemm_mfma_kernel<<<dim3(gemm_gx, 1), 256, 0, stream>>>(a16, WT, xl16, xr32, N, 64);
    agg_h1_kernel<<<agg_g, 256, 0, stream>>>(xl16, xr32, att3, b3, row_ptr, csr, out, N);
}